// Round 1
// baseline (647.949 us; speedup 1.0000x reference)
//
#include <hip/hip_runtime.h>

typedef __bf16 bf16x8 __attribute__((ext_vector_type(8)));
typedef float f32x4 __attribute__((ext_vector_type(4)));

constexpr int Sq = 2048, Dd = 1024, Hn = 16, Pn = 10, DK = 64;
constexpr int SKPAD = 2112;          // padded key axis (P + S = 2058 -> 2112)
constexpr int NBH = 64;              // B*H

__device__ __forceinline__ unsigned short f2bf(float f) {
  unsigned int u = __float_as_uint(f);
  u += 0x7fffu + ((u >> 16) & 1u);   // RNE
  return (unsigned short)(u >> 16);
}

__device__ __forceinline__ void gload_lds16(const void* g, void* l) {
  __builtin_amdgcn_global_load_lds(
      (const __attribute__((address_space(1))) void*)g,
      (__attribute__((address_space(3))) void*)l, 16, 0, 0);
}

__device__ __forceinline__ f32x4 mfma16(bf16x8 a, bf16x8 b, f32x4 c) {
  return __builtin_amdgcn_mfma_f32_16x16x32_bf16(a, b, c, 0, 0, 0);
}

// ---------------- fp32 -> bf16 convert (vectorized) ----------------
__global__ void k_cvt(const float* __restrict__ in, unsigned short* __restrict__ out, int n4) {
  int i = blockIdx.x * blockDim.x + threadIdx.x;
  int st = gridDim.x * blockDim.x;
  for (; i < n4; i += st) {
    float4 v = reinterpret_cast<const float4*>(in)[i];
    ushort4 r;
    r.x = f2bf(v.x); r.y = f2bf(v.y); r.z = f2bf(v.z); r.w = f2bf(v.w);
    reinterpret_cast<ushort4*>(out)[i] = r;
  }
}

// ---------------- W transpose + convert: Wt[n][k] = W[k][n] ----------------
__global__ void k_wt(const float* __restrict__ W0, const float* __restrict__ W1,
                     const float* __restrict__ W2, const float* __restrict__ W3,
                     unsigned short* __restrict__ T0, unsigned short* __restrict__ T1,
                     unsigned short* __restrict__ T2, unsigned short* __restrict__ T3) {
  __shared__ float tile[32][33];
  const float* W; unsigned short* T;
  switch (blockIdx.z) {
    case 0: W = W0; T = T0; break;
    case 1: W = W1; T = T1; break;
    case 2: W = W2; T = T2; break;
    default: W = W3; T = T3; break;
  }
  int n0 = blockIdx.x * 32, k0 = blockIdx.y * 32;
  int tx = threadIdx.x, ty = threadIdx.y;
  for (int r = ty; r < 32; r += 8)
    tile[r][tx] = W[(size_t)(k0 + r) * Dd + n0 + tx];
  __syncthreads();
  for (int r = ty; r < 32; r += 8)
    T[(size_t)(n0 + r) * Dd + k0 + tx] = f2bf(tile[tx][r]);
}

// ---------------- prefix K/V fill + zero padding ----------------
__global__ void k_fill(const float* __restrict__ pk, const float* __restrict__ pv,
                       unsigned short* __restrict__ Kb, unsigned short* __restrict__ Vt) {
  int bh = blockIdx.x;
  int h = bh & (Hn - 1);
  unsigned short* Kbh = Kb + (size_t)bh * SKPAD * DK;
  unsigned short* Vth = Vt + (size_t)bh * DK * SKPAD;
  for (int i = threadIdx.x; i < Pn * DK; i += blockDim.x) {
    int p = i >> 6, dk = i & 63;
    float kv = pk[((size_t)h * Pn + p) * DK + dk];
    float vv = pv[((size_t)h * Pn + p) * DK + dk];
    Kbh[p * DK + dk] = f2bf(kv);
    Vth[dk * SKPAD + p] = f2bf(vv);
  }
  constexpr int ZR = SKPAD - (Pn + Sq);  // 54 zero rows/cols
  for (int i = threadIdx.x; i < ZR * DK; i += blockDim.x) {
    int r = i >> 6, c = i & 63;
    Kbh[(Pn + Sq + r) * DK + c] = 0;
    Vth[c * SKPAD + (Pn + Sq + r)] = 0;
  }
}

// ---------------- GEMM: C[M,1024] = A[M,1024] @ Bt^T + bias ----------------
// Bt is N-major ([n][k]) so both operands load 8 contiguous k per lane.
// mode 0: Q -> [B,H,S,DK] bf16 (scale folded)   mode 1: K -> [B,H,SKPAD,DK] at +P
// mode 2: V -> [B,H,DK,SKPAD] at +P (transposed) mode 3: fp32 row-major out
__global__ __launch_bounds__(256, 2) void k_gemm(
    const unsigned short* __restrict__ A, const unsigned short* __restrict__ Bt,
    const float* __restrict__ bias, unsigned short* __restrict__ outB,
    float* __restrict__ outF, int mode, float scale) {
  __shared__ unsigned short As[128 * 64];
  __shared__ unsigned short Bs[128 * 64];
  int tid = threadIdx.x;
  int w = tid >> 6, l = tid & 63;
  int lq = l & 15, lg = l >> 4;
  int bx = blockIdx.x;
  int tm = bx >> 3, tn = bx & 7;
  int brow = tm * 128, bcol = tn * 128;
  int wm = w >> 1, wn = w & 1;

  f32x4 acc[4][4];
  for (int m = 0; m < 4; ++m)
    for (int n = 0; n < 4; ++n) acc[m][n] = (f32x4){0.f, 0.f, 0.f, 0.f};

  for (int kt = 0; kt < 1024; kt += 64) {
    for (int it = 0; it < 4; ++it) {
      int c = it * 256 + tid;
      int row = c >> 3, col = c & 7;
      gload_lds16(A + (size_t)(brow + row) * 1024 + kt + col * 8,
                  As + (size_t)(it * 256 + w * 64) * 8);
      gload_lds16(Bt + (size_t)(bcol + row) * 1024 + kt + col * 8,
                  Bs + (size_t)(it * 256 + w * 64) * 8);
    }
    asm volatile("s_waitcnt vmcnt(0)" ::: "memory");
    __syncthreads();
    const bf16x8* As8 = reinterpret_cast<const bf16x8*>(As);
    const bf16x8* Bs8 = reinterpret_cast<const bf16x8*>(Bs);
    for (int ks = 0; ks < 2; ++ks) {
      bf16x8 af[4], bfv[4];
      for (int m = 0; m < 4; ++m)
        af[m] = As8[(size_t)(wm * 64 + m * 16 + lq) * 8 + ks * 4 + lg];
      for (int n = 0; n < 4; ++n)
        bfv[n] = Bs8[(size_t)(wn * 64 + n * 16 + lq) * 8 + ks * 4 + lg];
      for (int m = 0; m < 4; ++m)
        for (int n = 0; n < 4; ++n)
          acc[m][n] = mfma16(af[m], bfv[n], acc[m][n]);
    }
    __syncthreads();
  }

  for (int n = 0; n < 4; ++n) {
    int N = bcol + wn * 64 + n * 16 + lq;
    float bv = bias[N];
    for (int m = 0; m < 4; ++m) {
      int M0 = brow + wm * 64 + m * 16 + lg * 4;
      for (int r = 0; r < 4; ++r) {
        float val = (acc[m][n][r] + bv) * scale;
        int Mr = M0 + r;
        if (mode == 3) {
          outF[(size_t)Mr * 1024 + N] = val;
        } else {
          int b = Mr >> 11, s = Mr & 2047;
          int h = N >> 6, dk = N & 63;
          size_t idx;
          if (mode == 0)      idx = (((size_t)(b * Hn + h)) * Sq + s) * DK + dk;
          else if (mode == 1) idx = (((size_t)(b * Hn + h)) * SKPAD + Pn + s) * DK + dk;
          else                idx = (((size_t)(b * Hn + h)) * DK + dk) * SKPAD + Pn + s;
          outB[idx] = f2bf(val);
        }
      }
    }
  }
}

// ---------------- flash attention with prefix + causal mask ----------------
// swapped QK^T (mfma(K,Q) -> S^T: lane-local q), P via per-wave swizzled LDS,
// non-swapped PV with V pre-transposed [dv][key]. K/V tiles XOR-swizzled via
// pre-swizzled global source (global_load_lds dest is linear).
__global__ __launch_bounds__(256, 2) void k_attn(
    const unsigned short* __restrict__ Qb, const unsigned short* __restrict__ Kb,
    const unsigned short* __restrict__ Vt, unsigned short* __restrict__ O) {
  __shared__ unsigned short Ks[64 * 64];
  __shared__ unsigned short Vs[64 * 64];
  __shared__ unsigned short Ps[4][16 * 64];
  int tid = threadIdx.x;
  int w = tid >> 6, l = tid & 63;
  int lq = l & 15, lg = l >> 4;
  int qb = blockIdx.x;
  int bh = blockIdx.y;
  int qs = qb * 64;

  const unsigned short* Qg = Qb + ((size_t)bh * Sq + qs + w * 16) * DK;
  bf16x8 qf[2];
  qf[0] = *reinterpret_cast<const bf16x8*>(Qg + (size_t)lq * DK + lg * 8);
  qf[1] = *reinterpret_cast<const bf16x8*>(Qg + (size_t)lq * DK + 32 + lg * 8);

  const unsigned short* Kg = Kb + (size_t)bh * SKPAD * DK;
  const unsigned short* Vg = Vt + (size_t)bh * DK * SKPAD;

  float m_run = -3e38f, l_run = 0.f;
  f32x4 oacc[4];
  for (int n = 0; n < 4; ++n) oacc[n] = (f32x4){0.f, 0.f, 0.f, 0.f};

  int qrow = qs + w * 16 + lq;
  int nkt = qb + 2;  // ceil((P + qs + 64)/64)
  unsigned short* Pw = &Ps[w][0];

  for (int t = 0; t < nkt; ++t) {
    int kt = t * 64;
    // K tile: contiguous 8KB; logical [key][dk], XOR-swizzle ((row&7)<<4)
    for (int it = 0; it < 2; ++it) {
      int dst = (it * 256 + tid) * 16;
      int src = dst ^ (((dst >> 7) & 7) << 4);
      gload_lds16((const char*)(Kg + (size_t)kt * DK) + src,
                  (char*)Ks + (size_t)(it * 256 + w * 64) * 16);
    }
    // V tile: logical [dv][key], rows strided SKPAD in global
    for (int it = 0; it < 2; ++it) {
      int dst = (it * 256 + tid) * 16;
      int row = dst >> 7;
      int colb = (dst & 127) ^ ((row & 7) << 4);
      gload_lds16((const char*)(Vg + (size_t)row * SKPAD + kt) + colb,
                  (char*)Vs + (size_t)(it * 256 + w * 64) * 16);
    }
    asm volatile("s_waitcnt vmcnt(0)" ::: "memory");
    __syncthreads();

    // S^T = K * Q : D[key][q], lane col = q = lq, rows key = m*16 + lg*4 + r
    f32x4 st[4];
    for (int m = 0; m < 4; ++m) st[m] = (f32x4){0.f, 0.f, 0.f, 0.f};
    for (int ks = 0; ks < 2; ++ks) {
      for (int m = 0; m < 4; ++m) {
        int krow = m * 16 + lq;
        int byt = (krow * 128 + ks * 64 + lg * 16) ^ ((krow & 7) << 4);
        bf16x8 kf = *reinterpret_cast<const bf16x8*>((const char*)Ks + byt);
        st[m] = mfma16(kf, qf[ks], st[m]);
      }
    }

    float mx = -3e38f;
    float sv[4][4];
    for (int m = 0; m < 4; ++m)
      for (int r = 0; r < 4; ++r) {
        int key = kt + m * 16 + lg * 4 + r;
        float x = st[m][r];
        x = (key <= qrow + Pn) ? x : -1e30f;
        sv[m][r] = x;
        mx = fmaxf(mx, x);
      }
    mx = fmaxf(mx, __shfl_xor(mx, 16));
    mx = fmaxf(mx, __shfl_xor(mx, 32));
    float mnew = fmaxf(m_run, mx);
    float alpha = __expf(m_run - mnew);
    m_run = mnew;
    float rs = 0.f;
    unsigned short pb[4][4];
    for (int m = 0; m < 4; ++m)
      for (int r = 0; r < 4; ++r) {
        float p = __expf(sv[m][r] - mnew);
        rs += p;
        pb[m][r] = f2bf(p);
      }
    rs += __shfl_xor(rs, 16);
    rs += __shfl_xor(rs, 32);
    l_run = l_run * alpha + rs;

    // write P^T back as [q][key] (swizzled), 4 consecutive keys = b64
    for (int m = 0; m < 4; ++m) {
      int byt = (lq * 128 + m * 32 + lg * 8) ^ ((lq & 7) << 4);
      ushort4 p4 = make_ushort4(pb[m][0], pb[m][1], pb[m][2], pb[m][3]);
      *reinterpret_cast<ushort4*>((char*)Pw + byt) = p4;
    }

    float ar[4];
    for (int r = 0; r < 4; ++r) ar[r] = __shfl(alpha, lg * 4 + r);
    for (int n = 0; n < 4; ++n)
      for (int r = 0; r < 4; ++r) oacc[n][r] *= ar[r];

    // O[q][dv] += P[q][key] @ V[key][dv]
    for (int ks = 0; ks < 2; ++ks) {
      int pbyt = (lq * 128 + ks * 64 + lg * 16) ^ ((lq & 7) << 4);
      bf16x8 pf = *reinterpret_cast<const bf16x8*>((const char*)Pw + pbyt);
      for (int n = 0; n < 4; ++n) {
        int dv = n * 16 + lq;
        int vbyt = (dv * 128 + ks * 64 + lg * 16) ^ ((dv & 7) << 4);
        bf16x8 vf = *reinterpret_cast<const bf16x8*>((const char*)Vs + vbyt);
        oacc[n] = mfma16(pf, vf, oacc[n]);
      }
    }
    __syncthreads();
  }

  float lr[4];
  for (int r = 0; r < 4; ++r) lr[r] = 1.0f / __shfl(l_run, lg * 4 + r);
  int b = bh >> 4, h = bh & 15;
  for (int n = 0; n < 4; ++n)
    for (int r = 0; r < 4; ++r) {
      int qrow2 = qs + w * 16 + lg * 4 + r;
      size_t idx = ((size_t)b * Sq + qrow2) * Dd + h * DK + n * 16 + lq;
      O[idx] = f2bf(oacc[n][r] * lr[r]);
    }
}

extern "C" void kernel_launch(void* const* d_in, const int* in_sizes, int n_in,
                              void* d_out, int out_size, void* d_ws, size_t ws_size,
                              hipStream_t stream) {
  (void)in_sizes; (void)n_in; (void)out_size; (void)ws_size;
  const float* q  = (const float*)d_in[0];
  const float* k  = (const float*)d_in[1];
  const float* v  = (const float*)d_in[2];
  const float* Wq = (const float*)d_in[4];
  const float* bq = (const float*)d_in[5];
  const float* Wk = (const float*)d_in[6];
  const float* bk = (const float*)d_in[7];
  const float* Wv = (const float*)d_in[8];
  const float* bv = (const float*)d_in[9];
  const float* Wo = (const float*)d_in[10];
  const float* bo = (const float*)d_in[11];
  const float* pk = (const float*)d_in[12];
  const float* pv = (const float*)d_in[13];

  unsigned short* wsp = (unsigned short*)d_ws;
  size_t off = 0;
  auto take = [&](size_t elems) { unsigned short* p = wsp + off; off += elems; return p; };
  unsigned short* qc  = take(8388608);
  unsigned short* kc  = take(8388608);
  unsigned short* vc  = take(8388608);
  unsigned short* wqt = take(1048576);
  unsigned short* wkt = take(1048576);
  unsigned short* wvt = take(1048576);
  unsigned short* wot = take(1048576);
  unsigned short* Qbf = take(8388608);
  unsigned short* KbB = take((size_t)NBH * SKPAD * DK);
  unsigned short* VtB = take((size_t)NBH * DK * SKPAD);
  unsigned short* Ob  = qc;  // reuse: qc dead once attention runs
  float* outF = (float*)d_out;

  k_cvt<<<2048, 256, 0, stream>>>(q, qc, 8388608 / 4);
  k_cvt<<<2048, 256, 0, stream>>>(k, kc, 8388608 / 4);
  k_cvt<<<2048, 256, 0, stream>>>(v, vc, 8388608 / 4);
  k_wt<<<dim3(32, 32, 4), dim3(32, 8), 0, stream>>>(Wq, Wk, Wv, Wo, wqt, wkt, wvt, wot);
  k_fill<<<64, 256, 0, stream>>>(pk, pv, KbB, VtB);
  k_gemm<<<512, 256, 0, stream>>>(qc, wqt, bq, Qbf, nullptr, 0, 0.125f);
  k_gemm<<<512, 256, 0, stream>>>(kc, wkt, bk, KbB, nullptr, 1, 1.0f);
  k_gemm<<<512, 256, 0, stream>>>(vc, wvt, bv, VtB, nullptr, 2, 1.0f);
  k_attn<<<dim3(32, NBH), 256, 0, stream>>>(Qbf, KbB, VtB, Ob);
  k_gemm<<<512, 256, 0, stream>>>(Ob, wot, bo, nullptr, outF, 3, 1.0f);
}

// Round 3
// 326.629 us; speedup vs baseline: 1.9837x; 1.9837x over previous
//
#include <hip/hip_runtime.h>

typedef __bf16 bf16x8 __attribute__((ext_vector_type(8)));
typedef float f32x4 __attribute__((ext_vector_type(4)));

constexpr int Sq = 2048, Dd = 1024, Hn = 16, Pn = 10, DK = 64;
constexpr int SKPAD = 2112;          // padded key axis (P + S = 2058 -> 2112)
constexpr int NBH = 64;              // B*H
constexpr float LOG2E = 1.44269504088896340736f;

__device__ __forceinline__ float exp2_fast(float x) {
  return __builtin_amdgcn_exp2f(x);  // v_exp_f32 computes 2^x natively
}

__device__ __forceinline__ unsigned short f2bf(float f) {
  unsigned int u = __float_as_uint(f);
  u += 0x7fffu + ((u >> 16) & 1u);   // RNE
  return (unsigned short)(u >> 16);
}

__device__ __forceinline__ void gload_lds16(const void* g, void* l) {
  __builtin_amdgcn_global_load_lds(
      (const __attribute__((address_space(1))) void*)g,
      (__attribute__((address_space(3))) void*)l, 16, 0, 0);
}

__device__ __forceinline__ f32x4 mfma16(bf16x8 a, bf16x8 b, f32x4 c) {
  return __builtin_amdgcn_mfma_f32_16x16x32_bf16(a, b, c, 0, 0, 0);
}

// ---------------- fp32 -> bf16 convert (3 tensors, one launch) ----------------
__global__ void k_cvt3(const float* __restrict__ i0, const float* __restrict__ i1,
                       const float* __restrict__ i2, unsigned short* __restrict__ o0,
                       unsigned short* __restrict__ o1, unsigned short* __restrict__ o2,
                       int n4) {
  const float* in; unsigned short* out;
  switch (blockIdx.y) {
    case 0: in = i0; out = o0; break;
    case 1: in = i1; out = o1; break;
    default: in = i2; out = o2; break;
  }
  int i = blockIdx.x * blockDim.x + threadIdx.x;
  int st = gridDim.x * blockDim.x;
  for (; i < n4; i += st) {
    float4 v = reinterpret_cast<const float4*>(in)[i];
    ushort4 r;
    r.x = f2bf(v.x); r.y = f2bf(v.y); r.z = f2bf(v.z); r.w = f2bf(v.w);
    reinterpret_cast<ushort4*>(out)[i] = r;
  }
}

// ---------------- W transpose + convert: Wt[n][k] = W[k][n] ----------------
__global__ void k_wt(const float* __restrict__ W0, const float* __restrict__ W1,
                     const float* __restrict__ W2, const float* __restrict__ W3,
                     unsigned short* __restrict__ T0, unsigned short* __restrict__ T1,
                     unsigned short* __restrict__ T2, unsigned short* __restrict__ T3) {
  __shared__ float tile[32][33];
  const float* W; unsigned short* T;
  switch (blockIdx.z) {
    case 0: W = W0; T = T0; break;
    case 1: W = W1; T = T1; break;
    case 2: W = W2; T = T2; break;
    default: W = W3; T = T3; break;
  }
  int n0 = blockIdx.x * 32, k0 = blockIdx.y * 32;
  int tx = threadIdx.x, ty = threadIdx.y;
  for (int r = ty; r < 32; r += 8)
    tile[r][tx] = W[(size_t)(k0 + r) * Dd + n0 + tx];
  __syncthreads();
  for (int r = ty; r < 32; r += 8)
    T[(size_t)(n0 + r) * Dd + k0 + tx] = f2bf(tile[tx][r]);
}

// ---------------- prefix K/V fill + zero padding ----------------
__global__ void k_fill(const float* __restrict__ pk, const float* __restrict__ pv,
                       unsigned short* __restrict__ Kb, unsigned short* __restrict__ Vt) {
  int bh = blockIdx.x;
  int h = bh & (Hn - 1);
  unsigned short* Kbh = Kb + (size_t)bh * SKPAD * DK;
  unsigned short* Vth = Vt + (size_t)bh * DK * SKPAD;
  for (int i = threadIdx.x; i < Pn * DK; i += blockDim.x) {
    int p = i >> 6, dk = i & 63;
    float kv = pk[((size_t)h * Pn + p) * DK + dk];
    float vv = pv[((size_t)h * Pn + p) * DK + dk];
    Kbh[p * DK + dk] = f2bf(kv);
    Vth[dk * SKPAD + p] = f2bf(vv);
  }
  constexpr int ZR = SKPAD - (Pn + Sq);  // 54 zero rows/cols
  for (int i = threadIdx.x; i < ZR * DK; i += blockDim.x) {
    int r = i >> 6, c = i & 63;
    Kbh[(Pn + Sq + r) * DK + c] = 0;
    Vth[c * SKPAD + (Pn + Sq + r)] = 0;
  }
}

// ---------------- GEMM: C[M,1024] = A[M,1024] @ Bt^T + bias ----------------
// 2-phase prefetch double-buffer (T3-minimum): stage next K-tile before compute.
// mode 0: Q -> [B,H,S,DK] bf16 (scale folded)   mode 1: K -> [B,H,SKPAD,DK] at +P
// mode 2: V -> [B,H,DK,SKPAD] at +P (transposed) mode 3: fp32 row-major out
__global__ __launch_bounds__(256, 2) void k_gemm(
    const unsigned short* __restrict__ A, const unsigned short* __restrict__ Bt,
    const float* __restrict__ bias, unsigned short* __restrict__ outB,
    float* __restrict__ outF, int mode, float scale) {
  __shared__ unsigned short As[2][128 * 64];
  __shared__ unsigned short Bs[2][128 * 64];
  int tid = threadIdx.x;
  int w = tid >> 6, l = tid & 63;
  int lq = l & 15, lg = l >> 4;
  int bx = blockIdx.x;
  int tm = bx >> 3, tn = bx & 7;
  int brow = tm * 128, bcol = tn * 128;
  int wm = w >> 1, wn = w & 1;

  f32x4 acc[4][4];
#pragma unroll
  for (int m = 0; m < 4; ++m)
#pragma unroll
    for (int n = 0; n < 4; ++n) acc[m][n] = (f32x4){0.f, 0.f, 0.f, 0.f};

  auto STAGE = [&](int b, int kt) {
#pragma unroll
    for (int it = 0; it < 4; ++it) {
      int c = it * 256 + tid;
      int row = c >> 3, col = c & 7;
      gload_lds16(A + (size_t)(brow + row) * 1024 + kt + col * 8,
                  As[b] + (size_t)(it * 256 + w * 64) * 8);
      gload_lds16(Bt + (size_t)(bcol + row) * 1024 + kt + col * 8,
                  Bs[b] + (size_t)(it * 256 + w * 64) * 8);
    }
  };

  STAGE(0, 0);
  asm volatile("s_waitcnt vmcnt(0)" ::: "memory");
  __syncthreads();

  for (int kt = 0; kt < 1024; kt += 64) {
    int b = (kt >> 6) & 1;
    if (kt + 64 < 1024) STAGE(b ^ 1, kt + 64);
    const bf16x8* As8 = reinterpret_cast<const bf16x8*>(As[b]);
    const bf16x8* Bs8 = reinterpret_cast<const bf16x8*>(Bs[b]);
#pragma unroll
    for (int ks = 0; ks < 2; ++ks) {
      bf16x8 af[4], bfv[4];
#pragma unroll
      for (int m = 0; m < 4; ++m)
        af[m] = As8[(size_t)(wm * 64 + m * 16 + lq) * 8 + ks * 4 + lg];
#pragma unroll
      for (int n = 0; n < 4; ++n)
        bfv[n] = Bs8[(size_t)(wn * 64 + n * 16 + lq) * 8 + ks * 4 + lg];
#pragma unroll
      for (int m = 0; m < 4; ++m)
#pragma unroll
        for (int n = 0; n < 4; ++n)
          acc[m][n] = mfma16(af[m], bfv[n], acc[m][n]);
    }
    asm volatile("s_waitcnt vmcnt(0)" ::: "memory");
    __syncthreads();
  }

#pragma unroll
  for (int n = 0; n < 4; ++n) {
    int N = bcol + wn * 64 + n * 16 + lq;
    float bv = bias[N];
#pragma unroll
    for (int m = 0; m < 4; ++m) {
      int M0 = brow + wm * 64 + m * 16 + lg * 4;
#pragma unroll
      for (int r = 0; r < 4; ++r) {
        float val = (acc[m][n][r] + bv) * scale;
        int Mr = M0 + r;
        if (mode == 3) {
          outF[(size_t)Mr * 1024 + N] = val;
        } else {
          int b = Mr >> 11, s = Mr & 2047;
          int h = N >> 6, dk = N & 63;
          size_t idx;
          if (mode == 0)      idx = (((size_t)(b * Hn + h)) * Sq + s) * DK + dk;
          else if (mode == 1) idx = (((size_t)(b * Hn + h)) * SKPAD + Pn + s) * DK + dk;
          else                idx = (((size_t)(b * Hn + h)) * DK + dk) * SKPAD + Pn + s;
          outB[idx] = f2bf(val);
        }
      }
    }
  }
}

// ---------------- flash attention with prefix + causal mask ----------------
// 4 waves x 32 q-rows (QBLK=128), KVBLK=64 double-buffered with 2-phase
// prefetch. Swapped QK^T (mfma(K,Q) -> S^T lane-local q), log2-domain online
// softmax with defer-rescale (T13), P via per-wave swizzled LDS, PV with V
// pre-transposed [dv][key]. K/V XOR-swizzled via pre-swizzled global source.
__global__ __launch_bounds__(256, 3) void k_attn(
    const unsigned short* __restrict__ Qb, const unsigned short* __restrict__ Kb,
    const unsigned short* __restrict__ Vt, unsigned short* __restrict__ O) {
  __shared__ unsigned short Ks[2][64 * 64];
  __shared__ unsigned short Vs[2][64 * 64];
  __shared__ unsigned short Ps[4][32 * 64];
  int tid = threadIdx.x;
  int w = tid >> 6, l = tid & 63;
  int lq = l & 15, lg = l >> 4;
  int qb = (gridDim.x - 1) - blockIdx.x;   // heavy blocks dispatch first
  int bh = blockIdx.y;
  int qs = qb * 128;
  int nkt = 2 * qb + 3;                    // ceil((P + qs + 128)/64)

  // Q fragments: rows qs + w*32 + nq*16 + lq, cols ks*32 + lg*8
  const unsigned short* Qg = Qb + ((size_t)bh * Sq + qs + w * 32) * DK;
  bf16x8 qf[2][2];
#pragma unroll
  for (int nq = 0; nq < 2; ++nq)
#pragma unroll
    for (int ks = 0; ks < 2; ++ks)
      qf[nq][ks] = *reinterpret_cast<const bf16x8*>(
          Qg + (size_t)(nq * 16 + lq) * DK + ks * 32 + lg * 8);

  const unsigned short* Kg = Kb + (size_t)bh * SKPAD * DK;
  const unsigned short* Vg = Vt + (size_t)bh * DK * SKPAD;

  float m_run[2] = {-1e30f, -1e30f};
  float l_run[2] = {0.f, 0.f};
  f32x4 oacc[2][4];
#pragma unroll
  for (int nq = 0; nq < 2; ++nq)
#pragma unroll
    for (int n = 0; n < 4; ++n) oacc[nq][n] = (f32x4){0.f, 0.f, 0.f, 0.f};

  unsigned short* Pw = &Ps[w][0];

  auto STAGE = [&](int b, int t) {
    int kt = t * 64;
#pragma unroll
    for (int it = 0; it < 2; ++it) {
      int dst = (it * 256 + tid) * 16;
      int srcK = dst ^ (((dst >> 7) & 7) << 4);
      gload_lds16((const char*)(Kg + (size_t)kt * DK) + srcK,
                  (char*)Ks[b] + (size_t)(it * 256 + w * 64) * 16);
    }
#pragma unroll
    for (int it = 0; it < 2; ++it) {
      int dst = (it * 256 + tid) * 16;
      int row = dst >> 7;
      int colb = (dst & 127) ^ ((row & 7) << 4);
      gload_lds16((const char*)(Vg + (size_t)row * SKPAD + kt) + colb,
                  (char*)Vs[b] + (size_t)(it * 256 + w * 64) * 16);
    }
  };

  STAGE(0, 0);
  asm volatile("s_waitcnt vmcnt(0)" ::: "memory");
  __syncthreads();

  for (int t = 0; t < nkt; ++t) {
    int bsel = t & 1;
    if (t + 1 < nkt) STAGE(bsel ^ 1, t + 1);
    int kt = t * 64;
    // wave-uniform: any key in this tile visible to this wave's 32 q-rows?
    bool active = (kt <= qs + w * 32 + 31 + Pn);
    if (active) {
      // S^T = K*Q : D[key][q], col q = lq, rows key = m*16 + lg*4 + r
      f32x4 st[4][2];
#pragma unroll
      for (int m = 0; m < 4; ++m)
#pragma unroll
        for (int nq = 0; nq < 2; ++nq) st[m][nq] = (f32x4){0.f, 0.f, 0.f, 0.f};
      __builtin_amdgcn_s_setprio(1);
#pragma unroll
      for (int ks = 0; ks < 2; ++ks) {
#pragma unroll
        for (int m = 0; m < 4; ++m) {
          int krow = m * 16 + lq;
          int byt = (krow * 128 + ks * 64 + lg * 16) ^ ((krow & 7) << 4);
          bf16x8 kf = *reinterpret_cast<const bf16x8*>((const char*)Ks[bsel] + byt);
          st[m][0] = mfma16(kf, qf[0][ks], st[m][0]);
          st[m][1] = mfma16(kf, qf[1][ks], st[m][1]);
        }
      }
      __builtin_amdgcn_s_setprio(0);

#pragma unroll
      for (int nq = 0; nq < 2; ++nq) {
        int qrow = qs + w * 32 + nq * 16 + lq;
        bool frag_masked = (kt + 63 > qs + w * 32 + nq * 16 + Pn);  // uniform
        float mx = -3e38f;
        float sv[16];
#pragma unroll
        for (int m = 0; m < 4; ++m)
#pragma unroll
          for (int r = 0; r < 4; ++r) {
            float x = st[m][nq][r];
            if (frag_masked) {
              int key = kt + m * 16 + lg * 4 + r;
              x = (key <= qrow + Pn) ? x : -1e30f;
            }
            sv[m * 4 + r] = x;
            mx = fmaxf(mx, x);
          }
        mx = fmaxf(mx, __shfl_xor(mx, 16));
        mx = fmaxf(mx, __shfl_xor(mx, 32));
        if (__any(mx > m_run[nq] + 8.f)) {   // T13 defer-rescale
          float mnew = fmaxf(m_run[nq], mx);
          float alpha = exp2_fast(m_run[nq] - mnew);
          m_run[nq] = mnew;
          l_run[nq] *= alpha;
          float ar[4];
#pragma unroll
          for (int r = 0; r < 4; ++r) ar[r] = __shfl(alpha, lg * 4 + r);
#pragma unroll
          for (int n = 0; n < 4; ++n)
#pragma unroll
            for (int r = 0; r < 4; ++r) oacc[nq][n][r] *= ar[r];
        }
        float rs = 0.f;
        unsigned short pb[16];
#pragma unroll
        for (int i = 0; i < 16; ++i) {
          float p = exp2_fast(sv[i] - m_run[nq]);
          rs += p;
          pb[i] = f2bf(p);
        }
        rs += __shfl_xor(rs, 16);
        rs += __shfl_xor(rs, 32);
        l_run[nq] += rs;
#pragma unroll
        for (int m = 0; m < 4; ++m) {
          int byt = ((nq * 16 + lq) * 128 + m * 32 + lg * 8) ^ ((lq & 7) << 4);
          *reinterpret_cast<ushort4*>((char*)Pw + byt) =
              make_ushort4(pb[m * 4], pb[m * 4 + 1], pb[m * 4 + 2], pb[m * 4 + 3]);
        }
      }

      // O[q][dv] += P[q][key] @ V[key][dv]
      __builtin_amdgcn_s_setprio(1);
#pragma unroll
      for (int ks = 0; ks < 2; ++ks) {
        int pb0 = ((lq) * 128 + ks * 64 + lg * 16) ^ ((lq & 7) << 4);
        int pb1 = ((16 + lq) * 128 + ks * 64 + lg * 16) ^ ((lq & 7) << 4);
        bf16x8 pf0 = *reinterpret_cast<const bf16x8*>((const char*)Pw + pb0);
        bf16x8 pf1 = *reinterpret_cast<const bf16x8*>((const char*)Pw + pb1);
#pragma unroll
        for (int n = 0; n < 4; ++n) {
          int dv = n * 16 + lq;
          int vbyt = (dv * 128 + ks * 64 + lg * 16) ^ ((dv & 7) << 4);
          bf16x8 vf = *reinterpret_cast<const bf16x8*>((const char*)Vs[bsel] + vbyt);
          oacc[0][n] = mfma16(pf0, vf, oacc[0][n]);
          oacc[1][n] = mfma16(pf1, vf, oacc[1][n]);
        }
      }
      __builtin_amdgcn_s_setprio(0);
    }
    asm volatile("s_waitcnt vmcnt(0)" ::: "memory");
    __syncthreads();
  }

  int b = bh >> 4, h = bh & 15;
#pragma unroll
  for (int nq = 0; nq < 2; ++nq) {
    float lr[4];
#pragma unroll
    for (int r = 0; r < 4; ++r) lr[r] = 1.0f / __shfl(l_run[nq], lg * 4 + r);
#pragma unroll
    for (int n = 0; n < 4; ++n)
#pragma unroll
      for (int r = 0; r < 4; ++r) {
        int qrow2 = qs + w * 32 + nq * 16 + lg * 4 + r;
        size_t idx = ((size_t)b * Sq + qrow2) * Dd + h * DK + n * 16 + lq;
        O[idx] = f2bf(oacc[nq][n][r] * lr[r]);
      }
  }
}

extern "C" void kernel_launch(void* const* d_in, const int* in_sizes, int n_in,
                              void* d_out, int out_size, void* d_ws, size_t ws_size,
                              hipStream_t stream) {
  (void)in_sizes; (void)n_in; (void)out_size; (void)ws_size;
  const float* q  = (const float*)d_in[0];
  const float* k  = (const float*)d_in[1];
  const float* v  = (const float*)d_in[2];
  const float* Wq = (const float*)d_in[4];
  const float* bq = (const float*)d_in[5];
  const float* Wk = (const float*)d_in[6];
  const float* bk = (const float*)d_in[7];
  const float* Wv = (const float*)d_in[8];
  const float* bv = (const float*)d_in[9];
  const float* Wo = (const float*)d_in[10];
  const float* bo = (const float*)d_in[11];
  const float* pk = (const float*)d_in[12];
  const float* pv = (const float*)d_in[13];

  unsigned short* wsp = (unsigned short*)d_ws;
  size_t off = 0;
  auto take = [&](size_t elems) { unsigned short* p = wsp + off; off += elems; return p; };
  unsigned short* qc  = take(8388608);
  unsigned short* kc  = take(8388608);
  unsigned short* vc  = take(8388608);
  unsigned short* wqt = take(1048576);
  unsigned short* wkt = take(1048576);
  unsigned short* wvt = take(1048576);
  unsigned short* wot = take(1048576);
  unsigned short* Qbf = take(8388608);
  unsigned short* KbB = take((size_t)NBH * SKPAD * DK);
  unsigned short* VtB = take((size_t)NBH * DK * SKPAD);
  unsigned short* Ob  = qc;  // reuse: qc dead once attention runs
  float* outF = (float*)d_out;

  k_cvt3<<<dim3(1024, 3), 256, 0, stream>>>(q, k, v, qc, kc, vc, 8388608 / 4);
  k_wt<<<dim3(32, 32, 4), dim3(32, 8), 0, stream>>>(Wq, Wk, Wv, Wo, wqt, wkt, wvt, wot);
  k_fill<<<64, 256, 0, stream>>>(pk, pv, KbB, VtB);
  // Q scale folds 1/sqrt(dk) AND log2(e) for the exp2-domain softmax
  k_gemm<<<512, 256, 0, stream>>>(qc, wqt, bq, Qbf, nullptr, 0, 0.125f * LOG2E);
  k_gemm<<<512, 256, 0, stream>>>(kc, wkt, bk, KbB, nullptr, 1, 1.0f);
  k_gemm<<<512, 256, 0, stream>>>(vc, wvt, bv, VtB, nullptr, 2, 1.0f);
  k_attn<<<dim3(16, NBH), 256, 0, stream>>>(Qbf, KbB, VtB, Ob);
  k_gemm<<<512, 256, 0, stream>>>(Ob, wot, bo, nullptr, outF, 3, 1.0f);
}

// Round 4
// 266.462 us; speedup vs baseline: 2.4317x; 1.2258x over previous
//
#include <hip/hip_runtime.h>

typedef __bf16 bf16x8 __attribute__((ext_vector_type(8)));
typedef float f32x4 __attribute__((ext_vector_type(4)));

constexpr int Sq = 2048, Dd = 1024, Hn = 16, Pn = 10, DK = 64;
constexpr int SKPAD = 2112;          // padded key axis (P + S = 2058 -> 2112)
constexpr int NBH = 64;              // B*H
constexpr float LOG2E = 1.44269504088896340736f;

__device__ __forceinline__ float exp2_fast(float x) {
  return __builtin_amdgcn_exp2f(x);  // v_exp_f32 computes 2^x natively
}

__device__ __forceinline__ unsigned short f2bf(float f) {
  unsigned int u = __float_as_uint(f);
  u += 0x7fffu + ((u >> 16) & 1u);   // RNE
  return (unsigned short)(u >> 16);
}

__device__ __forceinline__ void gload_lds16(const void* g, void* l) {
  __builtin_amdgcn_global_load_lds(
      (const __attribute__((address_space(1))) void*)g,
      (__attribute__((address_space(3))) void*)l, 16, 0, 0);
}

__device__ __forceinline__ f32x4 mfma16(bf16x8 a, bf16x8 b, f32x4 c) {
  return __builtin_amdgcn_mfma_f32_16x16x32_bf16(a, b, c, 0, 0, 0);
}

// ---------------- fp32 -> bf16 convert (3 tensors, one launch) ----------------
__global__ void k_cvt3(const float* __restrict__ i0, const float* __restrict__ i1,
                       const float* __restrict__ i2, unsigned short* __restrict__ o0,
                       unsigned short* __restrict__ o1, unsigned short* __restrict__ o2,
                       int n4) {
  const float* in; unsigned short* out;
  switch (blockIdx.y) {
    case 0: in = i0; out = o0; break;
    case 1: in = i1; out = o1; break;
    default: in = i2; out = o2; break;
  }
  int i = blockIdx.x * blockDim.x + threadIdx.x;
  int st = gridDim.x * blockDim.x;
  for (; i < n4; i += st) {
    float4 v = reinterpret_cast<const float4*>(in)[i];
    ushort4 r;
    r.x = f2bf(v.x); r.y = f2bf(v.y); r.z = f2bf(v.z); r.w = f2bf(v.w);
    reinterpret_cast<ushort4*>(out)[i] = r;
  }
}

// ---------------- W transpose + convert: Wt[n][k] = W[k][n] ----------------
__global__ void k_wt(const float* __restrict__ W0, const float* __restrict__ W1,
                     const float* __restrict__ W2, const float* __restrict__ W3,
                     unsigned short* __restrict__ T0, unsigned short* __restrict__ T1,
                     unsigned short* __restrict__ T2, unsigned short* __restrict__ T3) {
  __shared__ float tile[32][33];
  const float* W; unsigned short* T;
  switch (blockIdx.z) {
    case 0: W = W0; T = T0; break;
    case 1: W = W1; T = T1; break;
    case 2: W = W2; T = T2; break;
    default: W = W3; T = T3; break;
  }
  int n0 = blockIdx.x * 32, k0 = blockIdx.y * 32;
  int tx = threadIdx.x, ty = threadIdx.y;
  for (int r = ty; r < 32; r += 8)
    tile[r][tx] = W[(size_t)(k0 + r) * Dd + n0 + tx];
  __syncthreads();
  for (int r = ty; r < 32; r += 8)
    T[(size_t)(n0 + r) * Dd + k0 + tx] = f2bf(tile[tx][r]);
}

// ---------------- prefix K/V fill + zero padding ----------------
__global__ void k_fill(const float* __restrict__ pk, const float* __restrict__ pv,
                       unsigned short* __restrict__ Kb, unsigned short* __restrict__ Vt) {
  int bh = blockIdx.x;
  int h = bh & (Hn - 1);
  unsigned short* Kbh = Kb + (size_t)bh * SKPAD * DK;
  unsigned short* Vth = Vt + (size_t)bh * DK * SKPAD;
  for (int i = threadIdx.x; i < Pn * DK; i += blockDim.x) {
    int p = i >> 6, dk = i & 63;
    float kv = pk[((size_t)h * Pn + p) * DK + dk];
    float vv = pv[((size_t)h * Pn + p) * DK + dk];
    Kbh[p * DK + dk] = f2bf(kv);
    Vth[dk * SKPAD + p] = f2bf(vv);
  }
  constexpr int ZR = SKPAD - (Pn + Sq);  // 54 zero rows/cols
  for (int i = threadIdx.x; i < ZR * DK; i += blockDim.x) {
    int r = i >> 6, c = i & 63;
    Kbh[(Pn + Sq + r) * DK + c] = 0;
    Vth[c * SKPAD + (Pn + Sq + r)] = 0;
  }
}

// ---------------- GEMM: C[M,1024] = A[M,1024] @ Bt^T + bias ----------------
// 2-phase prefetch double-buffer (T3-minimum): stage next K-tile before compute.
// mode 0: Q -> [B,H,S,DK] bf16 (scale folded)   mode 1: K -> [B,H,SKPAD,DK] at +P
// mode 2: V -> [B,H,DK,SKPAD] at +P (transposed) mode 3: fp32 row-major out
__global__ __launch_bounds__(256, 2) void k_gemm(
    const unsigned short* __restrict__ A, const unsigned short* __restrict__ Bt,
    const float* __restrict__ bias, unsigned short* __restrict__ outB,
    float* __restrict__ outF, int mode, float scale) {
  __shared__ unsigned short As[2][128 * 64];
  __shared__ unsigned short Bs[2][128 * 64];
  int tid = threadIdx.x;
  int w = tid >> 6, l = tid & 63;
  int lq = l & 15, lg = l >> 4;
  int bx = blockIdx.x;
  int tm = bx >> 3, tn = bx & 7;
  int brow = tm * 128, bcol = tn * 128;
  int wm = w >> 1, wn = w & 1;

  f32x4 acc[4][4];
#pragma unroll
  for (int m = 0; m < 4; ++m)
#pragma unroll
    for (int n = 0; n < 4; ++n) acc[m][n] = (f32x4){0.f, 0.f, 0.f, 0.f};

  auto STAGE = [&](int b, int kt) {
#pragma unroll
    for (int it = 0; it < 4; ++it) {
      int c = it * 256 + tid;
      int row = c >> 3, col = c & 7;
      gload_lds16(A + (size_t)(brow + row) * 1024 + kt + col * 8,
                  As[b] + (size_t)(it * 256 + w * 64) * 8);
      gload_lds16(Bt + (size_t)(bcol + row) * 1024 + kt + col * 8,
                  Bs[b] + (size_t)(it * 256 + w * 64) * 8);
    }
  };

  STAGE(0, 0);
  asm volatile("s_waitcnt vmcnt(0)" ::: "memory");
  __syncthreads();

  for (int kt = 0; kt < 1024; kt += 64) {
    int b = (kt >> 6) & 1;
    if (kt + 64 < 1024) STAGE(b ^ 1, kt + 64);
    const bf16x8* As8 = reinterpret_cast<const bf16x8*>(As[b]);
    const bf16x8* Bs8 = reinterpret_cast<const bf16x8*>(Bs[b]);
#pragma unroll
    for (int ks = 0; ks < 2; ++ks) {
      bf16x8 af[4], bfv[4];
#pragma unroll
      for (int m = 0; m < 4; ++m)
        af[m] = As8[(size_t)(wm * 64 + m * 16 + lq) * 8 + ks * 4 + lg];
#pragma unroll
      for (int n = 0; n < 4; ++n)
        bfv[n] = Bs8[(size_t)(wn * 64 + n * 16 + lq) * 8 + ks * 4 + lg];
#pragma unroll
      for (int m = 0; m < 4; ++m)
#pragma unroll
        for (int n = 0; n < 4; ++n)
          acc[m][n] = mfma16(af[m], bfv[n], acc[m][n]);
    }
    asm volatile("s_waitcnt vmcnt(0)" ::: "memory");
    __syncthreads();
  }

#pragma unroll
  for (int n = 0; n < 4; ++n) {
    int N = bcol + wn * 64 + n * 16 + lq;
    float bv = bias[N];
#pragma unroll
    for (int m = 0; m < 4; ++m) {
      int M0 = brow + wm * 64 + m * 16 + lg * 4;
#pragma unroll
      for (int r = 0; r < 4; ++r) {
        float val = (acc[m][n][r] + bv) * scale;
        int Mr = M0 + r;
        if (mode == 3) {
          outF[(size_t)Mr * 1024 + N] = val;
        } else {
          int b = Mr >> 11, s = Mr & 2047;
          int h = N >> 6, dk = N & 63;
          size_t idx;
          if (mode == 0)      idx = (((size_t)(b * Hn + h)) * Sq + s) * DK + dk;
          else if (mode == 1) idx = (((size_t)(b * Hn + h)) * SKPAD + Pn + s) * DK + dk;
          else                idx = (((size_t)(b * Hn + h)) * DK + dk) * SKPAD + Pn + s;
          outB[idx] = f2bf(val);
        }
      }
    }
  }
}

// ---------------- flash attention with prefix + causal mask ----------------
// Trapezoid-paired blocks: each block owns q-tiles {bx, 15-bx} (36 key-tiles
// of compute, uniform by construction) processed SIMULTANEOUSLY over one
// shared K/V staging stream (K/V staged once per key-tile for both q-tiles).
// 4 waves x 32 q-rows per q-tile, KVBLK=64 double-buffered 2-phase prefetch.
// Swapped QK^T (mfma(K,Q) -> S^T lane-local q), log2-domain online softmax
// with defer-rescale (T13), P via per-wave swizzled LDS (reused across the
// two q-streams), PV with V pre-transposed [dv][key]. K/V XOR-swizzled via
// pre-swizzled global source (global_load_lds dest is linear).
__global__ __launch_bounds__(256, 2) void k_attn(
    const unsigned short* __restrict__ Qb, const unsigned short* __restrict__ Kb,
    const unsigned short* __restrict__ Vt, unsigned short* __restrict__ O) {
  __shared__ unsigned short Ks[2][64 * 64];
  __shared__ unsigned short Vs[2][64 * 64];
  __shared__ unsigned short Ps[4][32 * 64];
  int tid = threadIdx.x;
  int w = tid >> 6, l = tid & 63;
  int lq = l & 15, lg = l >> 4;
  int bx = blockIdx.x;           // 0..7
  int bh = blockIdx.y;
  int qbL = bx, qbH = 15 - bx;
  int nktL = 2 * qbL + 3;
  int nktH = 2 * qbH + 3;
  int qsA[2] = {qbL * 128, qbH * 128};

  // Q fragments for both q-tiles: rows qs + w*32 + nq*16 + lq, cols ks*32+lg*8
  bf16x8 qf[2][2][2];
#pragma unroll
  for (int qt = 0; qt < 2; ++qt) {
    const unsigned short* Qg = Qb + ((size_t)bh * Sq + qsA[qt] + w * 32) * DK;
#pragma unroll
    for (int nq = 0; nq < 2; ++nq)
#pragma unroll
      for (int ks = 0; ks < 2; ++ks)
        qf[qt][nq][ks] = *reinterpret_cast<const bf16x8*>(
            Qg + (size_t)(nq * 16 + lq) * DK + ks * 32 + lg * 8);
  }

  const unsigned short* Kg = Kb + (size_t)bh * SKPAD * DK;
  const unsigned short* Vg = Vt + (size_t)bh * DK * SKPAD;

  float m_run[2][2] = {{-1e30f, -1e30f}, {-1e30f, -1e30f}};
  float l_run[2][2] = {{0.f, 0.f}, {0.f, 0.f}};
  f32x4 oacc[2][2][4];
#pragma unroll
  for (int qt = 0; qt < 2; ++qt)
#pragma unroll
    for (int nq = 0; nq < 2; ++nq)
#pragma unroll
      for (int n = 0; n < 4; ++n) oacc[qt][nq][n] = (f32x4){0.f, 0.f, 0.f, 0.f};

  unsigned short* Pw = &Ps[w][0];

  auto STAGE = [&](int b, int t) {
    int kt = t * 64;
#pragma unroll
    for (int it = 0; it < 2; ++it) {
      int dst = (it * 256 + tid) * 16;
      int srcK = dst ^ (((dst >> 7) & 7) << 4);
      gload_lds16((const char*)(Kg + (size_t)kt * DK) + srcK,
                  (char*)Ks[b] + (size_t)(it * 256 + w * 64) * 16);
    }
#pragma unroll
    for (int it = 0; it < 2; ++it) {
      int dst = (it * 256 + tid) * 16;
      int row = dst >> 7;
      int colb = (dst & 127) ^ ((row & 7) << 4);
      gload_lds16((const char*)(Vg + (size_t)row * SKPAD + kt) + colb,
                  (char*)Vs[b] + (size_t)(it * 256 + w * 64) * 16);
    }
  };

  STAGE(0, 0);
  asm volatile("s_waitcnt vmcnt(0)" ::: "memory");
  __syncthreads();

  for (int t = 0; t < nktH; ++t) {
    int bsel = t & 1;
    if (t + 1 < nktH) STAGE(bsel ^ 1, t + 1);
    int kt = t * 64;

#pragma unroll
    for (int qt = 0; qt < 2; ++qt) {
      if (qt == 0 && t >= nktL) continue;       // light stream exhausted
      int qs = qsA[qt];
      // wave-uniform: any key in this tile visible to this wave's 32 q-rows?
      if (kt > qs + w * 32 + 31 + Pn) continue;

      // S^T = K*Q : D[key][q], col q = lq, rows key = m*16 + lg*4 + r
      f32x4 st[4][2];
#pragma unroll
      for (int m = 0; m < 4; ++m)
#pragma unroll
        for (int nq = 0; nq < 2; ++nq) st[m][nq] = (f32x4){0.f, 0.f, 0.f, 0.f};
      __builtin_amdgcn_s_setprio(1);
#pragma unroll
      for (int ks = 0; ks < 2; ++ks) {
#pragma unroll
        for (int m = 0; m < 4; ++m) {
          int krow = m * 16 + lq;
          int byt = (krow * 128 + ks * 64 + lg * 16) ^ ((krow & 7) << 4);
          bf16x8 kf = *reinterpret_cast<const bf16x8*>((const char*)Ks[bsel] + byt);
          st[m][0] = mfma16(kf, qf[qt][0][ks], st[m][0]);
          st[m][1] = mfma16(kf, qf[qt][1][ks], st[m][1]);
        }
      }
      __builtin_amdgcn_s_setprio(0);

#pragma unroll
      for (int nq = 0; nq < 2; ++nq) {
        int qrow = qs + w * 32 + nq * 16 + lq;
        bool frag_masked = (kt + 63 > qs + w * 32 + nq * 16 + Pn);  // uniform
        float mx = -3e38f;
        float sv[16];
#pragma unroll
        for (int m = 0; m < 4; ++m)
#pragma unroll
          for (int r = 0; r < 4; ++r) {
            float x = st[m][nq][r];
            if (frag_masked) {
              int key = kt + m * 16 + lg * 4 + r;
              x = (key <= qrow + Pn) ? x : -1e30f;
            }
            sv[m * 4 + r] = x;
            mx = fmaxf(mx, x);
          }
        mx = fmaxf(mx, __shfl_xor(mx, 16));
        mx = fmaxf(mx, __shfl_xor(mx, 32));
        if (__any(mx > m_run[qt][nq] + 8.f)) {   // T13 defer-rescale
          float mnew = fmaxf(m_run[qt][nq], mx);
          float alpha = exp2_fast(m_run[qt][nq] - mnew);
          m_run[qt][nq] = mnew;
          l_run[qt][nq] *= alpha;
          float ar[4];
#pragma unroll
          for (int r = 0; r < 4; ++r) ar[r] = __shfl(alpha, lg * 4 + r);
#pragma unroll
          for (int n = 0; n < 4; ++n)
#pragma unroll
            for (int r = 0; r < 4; ++r) oacc[qt][nq][n][r] *= ar[r];
        }
        float rs = 0.f;
        unsigned short pb[16];
#pragma unroll
        for (int i = 0; i < 16; ++i) {
          float p = exp2_fast(sv[i] - m_run[qt][nq]);
          rs += p;
          pb[i] = f2bf(p);
        }
        rs += __shfl_xor(rs, 16);
        rs += __shfl_xor(rs, 32);
        l_run[qt][nq] += rs;
#pragma unroll
        for (int m = 0; m < 4; ++m) {
          int byt = ((nq * 16 + lq) * 128 + m * 32 + lg * 8) ^ ((lq & 7) << 4);
          *reinterpret_cast<ushort4*>((char*)Pw + byt) =
              make_ushort4(pb[m * 4], pb[m * 4 + 1], pb[m * 4 + 2], pb[m * 4 + 3]);
        }
      }

      // O[q][dv] += P[q][key] @ V[key][dv]
      __builtin_amdgcn_s_setprio(1);
#pragma unroll
      for (int ks = 0; ks < 2; ++ks) {
        int pb0 = ((lq) * 128 + ks * 64 + lg * 16) ^ ((lq & 7) << 4);
        int pb1 = ((16 + lq) * 128 + ks * 64 + lg * 16) ^ ((lq & 7) << 4);
        bf16x8 pf0 = *reinterpret_cast<const bf16x8*>((const char*)Pw + pb0);
        bf16x8 pf1 = *reinterpret_cast<const bf16x8*>((const char*)Pw + pb1);
#pragma unroll
        for (int n = 0; n < 4; ++n) {
          int dv = n * 16 + lq;
          int vbyt = (dv * 128 + ks * 64 + lg * 16) ^ ((dv & 7) << 4);
          bf16x8 vf = *reinterpret_cast<const bf16x8*>((const char*)Vs[bsel] + vbyt);
          oacc[qt][0][n] = mfma16(pf0, vf, oacc[qt][0][n]);
          oacc[qt][1][n] = mfma16(pf1, vf, oacc[qt][1][n]);
        }
      }
      __builtin_amdgcn_s_setprio(0);
    }
    asm volatile("s_waitcnt vmcnt(0)" ::: "memory");
    __syncthreads();
  }

  int b = bh >> 4, h = bh & 15;
#pragma unroll
  for (int qt = 0; qt < 2; ++qt) {
#pragma unroll
    for (int nq = 0; nq < 2; ++nq) {
      float lr[4];
#pragma unroll
      for (int r = 0; r < 4; ++r) lr[r] = 1.0f / __shfl(l_run[qt][nq], lg * 4 + r);
#pragma unroll
      for (int n = 0; n < 4; ++n)
#pragma unroll
        for (int r = 0; r < 4; ++r) {
          int qrow2 = qsA[qt] + w * 32 + nq * 16 + lg * 4 + r;
          size_t idx = ((size_t)b * Sq + qrow2) * Dd + h * DK + n * 16 + lq;
          O[idx] = f2bf(oacc[qt][nq][n][r] * lr[r]);
        }
    }
  }
}

extern "C" void kernel_launch(void* const* d_in, const int* in_sizes, int n_in,
                              void* d_out, int out_size, void* d_ws, size_t ws_size,
                              hipStream_t stream) {
  (void)in_sizes; (void)n_in; (void)out_size; (void)ws_size;
  const float* q  = (const float*)d_in[0];
  const float* k  = (const float*)d_in[1];
  const float* v  = (const float*)d_in[2];
  const float* Wq = (const float*)d_in[4];
  const float* bq = (const float*)d_in[5];
  const float* Wk = (const float*)d_in[6];
  const float* bk = (const float*)d_in[7];
  const float* Wv = (const float*)d_in[8];
  const float* bv = (const float*)d_in[9];
  const float* Wo = (const float*)d_in[10];
  const float* bo = (const float*)d_in[11];
  const float* pk = (const float*)d_in[12];
  const float* pv = (const float*)d_in[13];

  unsigned short* wsp = (unsigned short*)d_ws;
  size_t off = 0;
  auto take = [&](size_t elems) { unsigned short* p = wsp + off; off += elems; return p; };
  unsigned short* qc  = take(8388608);
  unsigned short* kc  = take(8388608);
  unsigned short* vc  = take(8388608);
  unsigned short* wqt = take(1048576);
  unsigned short* wkt = take(1048576);
  unsigned short* wvt = take(1048576);
  unsigned short* wot = take(1048576);
  unsigned short* Qbf = take(8388608);
  unsigned short* KbB = take((size_t)NBH * SKPAD * DK);
  unsigned short* VtB = take((size_t)NBH * DK * SKPAD);
  unsigned short* Ob  = qc;  // reuse: qc dead once attention runs
  float* outF = (float*)d_out;

  k_cvt3<<<dim3(1024, 3), 256, 0, stream>>>(q, k, v, qc, kc, vc, 8388608 / 4);
  k_wt<<<dim3(32, 32, 4), dim3(32, 8), 0, stream>>>(Wq, Wk, Wv, Wo, wqt, wkt, wvt, wot);
  k_fill<<<64, 256, 0, stream>>>(pk, pv, KbB, VtB);
  // Q scale folds 1/sqrt(dk) AND log2(e) for the exp2-domain softmax
  k_gemm<<<512, 256, 0, stream>>>(qc, wqt, bq, Qbf, nullptr, 0, 0.125f * LOG2E);
  k_gemm<<<512, 256, 0, stream>>>(kc, wkt, bk, KbB, nullptr, 1, 1.0f);
  k_gemm<<<512, 256, 0, stream>>>(vc, wvt, bv, VtB, nullptr, 2, 1.0f);
  k_attn<<<dim3(8, NBH), 256, 0, stream>>>(Qbf, KbB, VtB, Ob);
  k_gemm<<<512, 256, 0, stream>>>(Ob, wot, bo, nullptr, outF, 3, 1.0f);
}

// Round 5
// 246.677 us; speedup vs baseline: 2.6267x; 1.0802x over previous
//
#include <hip/hip_runtime.h>

typedef __bf16 bf16x8 __attribute__((ext_vector_type(8)));
typedef __bf16 bf16x4 __attribute__((ext_vector_type(4)));
typedef float f32x4 __attribute__((ext_vector_type(4)));

constexpr int Sq = 2048, Dd = 1024, Hn = 16, Pn = 10, DK = 64;
constexpr int SKPAD = 2112;          // padded key axis (P + S = 2058 -> 2112)
constexpr int NBH = 64;              // B*H
constexpr float LOG2E = 1.44269504088896340736f;

__device__ __forceinline__ float exp2_fast(float x) {
  return __builtin_amdgcn_exp2f(x);  // v_exp_f32 computes 2^x natively
}

__device__ __forceinline__ unsigned short f2bf(float f) {
  unsigned int u = __float_as_uint(f);
  u += 0x7fffu + ((u >> 16) & 1u);   // RNE
  return (unsigned short)(u >> 16);
}

__device__ __forceinline__ void gload_lds16(const void* g, void* l) {
  __builtin_amdgcn_global_load_lds(
      (const __attribute__((address_space(1))) void*)g,
      (__attribute__((address_space(3))) void*)l, 16, 0, 0);
}

__device__ __forceinline__ f32x4 mfma16(bf16x8 a, bf16x8 b, f32x4 c) {
  return __builtin_amdgcn_mfma_f32_16x16x32_bf16(a, b, c, 0, 0, 0);
}

// ---------------- fp32 -> bf16 convert (3 tensors, one launch) ----------------
__global__ void k_cvt3(const float* __restrict__ i0, const float* __restrict__ i1,
                       const float* __restrict__ i2, unsigned short* __restrict__ o0,
                       unsigned short* __restrict__ o1, unsigned short* __restrict__ o2,
                       int n4) {
  const float* in; unsigned short* out;
  switch (blockIdx.y) {
    case 0: in = i0; out = o0; break;
    case 1: in = i1; out = o1; break;
    default: in = i2; out = o2; break;
  }
  int i = blockIdx.x * blockDim.x + threadIdx.x;
  int st = gridDim.x * blockDim.x;
  for (; i < n4; i += st) {
    float4 v = reinterpret_cast<const float4*>(in)[i];
    ushort4 r;
    r.x = f2bf(v.x); r.y = f2bf(v.y); r.z = f2bf(v.z); r.w = f2bf(v.w);
    reinterpret_cast<ushort4*>(out)[i] = r;
  }
}

// ---------------- W transpose + convert: Wt[n][k] = W[k][n] ----------------
__global__ void k_wt(const float* __restrict__ W0, const float* __restrict__ W1,
                     const float* __restrict__ W2, const float* __restrict__ W3,
                     unsigned short* __restrict__ T0, unsigned short* __restrict__ T1,
                     unsigned short* __restrict__ T2, unsigned short* __restrict__ T3) {
  __shared__ float tile[32][33];
  const float* W; unsigned short* T;
  switch (blockIdx.z) {
    case 0: W = W0; T = T0; break;
    case 1: W = W1; T = T1; break;
    case 2: W = W2; T = T2; break;
    default: W = W3; T = T3; break;
  }
  int n0 = blockIdx.x * 32, k0 = blockIdx.y * 32;
  int tx = threadIdx.x, ty = threadIdx.y;
  for (int r = ty; r < 32; r += 8)
    tile[r][tx] = W[(size_t)(k0 + r) * Dd + n0 + tx];
  __syncthreads();
  for (int r = ty; r < 32; r += 8)
    T[(size_t)(n0 + r) * Dd + k0 + tx] = f2bf(tile[tx][r]);
}

// ---------------- prefix K/V fill + zero padding ----------------
__global__ void k_fill(const float* __restrict__ pk, const float* __restrict__ pv,
                       unsigned short* __restrict__ Kb, unsigned short* __restrict__ Vt) {
  int bh = blockIdx.x;
  int h = bh & (Hn - 1);
  unsigned short* Kbh = Kb + (size_t)bh * SKPAD * DK;
  unsigned short* Vth = Vt + (size_t)bh * DK * SKPAD;
  for (int i = threadIdx.x; i < Pn * DK; i += blockDim.x) {
    int p = i >> 6, dk = i & 63;
    float kv = pk[((size_t)h * Pn + p) * DK + dk];
    float vv = pv[((size_t)h * Pn + p) * DK + dk];
    Kbh[p * DK + dk] = f2bf(kv);
    Vth[dk * SKPAD + p] = f2bf(vv);
  }
  constexpr int ZR = SKPAD - (Pn + Sq);  // 54 zero rows/cols
  for (int i = threadIdx.x; i < ZR * DK; i += blockDim.x) {
    int r = i >> 6, c = i & 63;
    Kbh[(Pn + Sq + r) * DK + c] = 0;
    Vth[c * SKPAD + (Pn + Sq + r)] = 0;
  }
}

// ---------------- GEMM: C[M,1024] = A[M,1024] @ Bt^T + bias ----------------
// 2-phase prefetch double-buffer (T3-minimum): stage next K-tile before compute.
// mode 0: Q -> [B,H,S,DK] bf16 (scale folded)   mode 1: K -> [B,H,SKPAD,DK] at +P
// mode 2: V -> [B,H,DK,SKPAD] at +P (transposed) mode 3: fp32 row-major out
__global__ __launch_bounds__(256, 2) void k_gemm(
    const unsigned short* __restrict__ A, const unsigned short* __restrict__ Bt,
    const float* __restrict__ bias, unsigned short* __restrict__ outB,
    float* __restrict__ outF, int mode, float scale) {
  __shared__ unsigned short As[2][128 * 64];
  __shared__ unsigned short Bs[2][128 * 64];
  int tid = threadIdx.x;
  int w = tid >> 6, l = tid & 63;
  int lq = l & 15, lg = l >> 4;
  int bx = blockIdx.x;
  int tm = bx >> 3, tn = bx & 7;
  int brow = tm * 128, bcol = tn * 128;
  int wm = w >> 1, wn = w & 1;

  f32x4 acc[4][4];
#pragma unroll
  for (int m = 0; m < 4; ++m)
#pragma unroll
    for (int n = 0; n < 4; ++n) acc[m][n] = (f32x4){0.f, 0.f, 0.f, 0.f};

  auto STAGE = [&](int b, int kt) {
#pragma unroll
    for (int it = 0; it < 4; ++it) {
      int c = it * 256 + tid;
      int row = c >> 3, col = c & 7;
      gload_lds16(A + (size_t)(brow + row) * 1024 + kt + col * 8,
                  As[b] + (size_t)(it * 256 + w * 64) * 8);
      gload_lds16(Bt + (size_t)(bcol + row) * 1024 + kt + col * 8,
                  Bs[b] + (size_t)(it * 256 + w * 64) * 8);
    }
  };

  STAGE(0, 0);
  asm volatile("s_waitcnt vmcnt(0)" ::: "memory");
  __syncthreads();

  for (int kt = 0; kt < 1024; kt += 64) {
    int b = (kt >> 6) & 1;
    if (kt + 64 < 1024) STAGE(b ^ 1, kt + 64);
    const bf16x8* As8 = reinterpret_cast<const bf16x8*>(As[b]);
    const bf16x8* Bs8 = reinterpret_cast<const bf16x8*>(Bs[b]);
#pragma unroll
    for (int ks = 0; ks < 2; ++ks) {
      bf16x8 af[4], bfv[4];
#pragma unroll
      for (int m = 0; m < 4; ++m)
        af[m] = As8[(size_t)(wm * 64 + m * 16 + lq) * 8 + ks * 4 + lg];
#pragma unroll
      for (int n = 0; n < 4; ++n)
        bfv[n] = Bs8[(size_t)(wn * 64 + n * 16 + lq) * 8 + ks * 4 + lg];
#pragma unroll
      for (int m = 0; m < 4; ++m)
#pragma unroll
        for (int n = 0; n < 4; ++n)
          acc[m][n] = mfma16(af[m], bfv[n], acc[m][n]);
    }
    asm volatile("s_waitcnt vmcnt(0)" ::: "memory");
    __syncthreads();
  }

#pragma unroll
  for (int n = 0; n < 4; ++n) {
    int N = bcol + wn * 64 + n * 16 + lq;
    float bv = bias[N];
#pragma unroll
    for (int m = 0; m < 4; ++m) {
      int M0 = brow + wm * 64 + m * 16 + lg * 4;
#pragma unroll
      for (int r = 0; r < 4; ++r) {
        float val = (acc[m][n][r] + bv) * scale;
        int Mr = M0 + r;
        if (mode == 3) {
          outF[(size_t)Mr * 1024 + N] = val;
        } else {
          int b = Mr >> 11, s = Mr & 2047;
          int h = N >> 6, dk = N & 63;
          size_t idx;
          if (mode == 0)      idx = (((size_t)(b * Hn + h)) * Sq + s) * DK + dk;
          else if (mode == 1) idx = (((size_t)(b * Hn + h)) * SKPAD + Pn + s) * DK + dk;
          else                idx = (((size_t)(b * Hn + h)) * DK + dk) * SKPAD + Pn + s;
          outB[idx] = f2bf(val);
        }
      }
    }
  }
}

// ---------------- flash attention with prefix + causal mask ----------------
// Paired 64-row q-tiles {pi, 31-pi}: uniform 35 key-tiles/block; both streams
// share one K/V staging stream (staged once per key-tile). Grid is bh-major so
// all 16 blocks of a head land on the same XCD (L2 locality for that head's
// K/V). 4 waves x 16 q-rows per stream, KVBLK=64 double-buffered 2-phase
// prefetch. Swapped QK^T (mfma(K,Q) -> S^T lane-local q), log2-domain online
// softmax with defer-rescale (T13), P via per-wave swizzled LDS, PV with V
// pre-transposed [dv][key]. K/V XOR-swizzled via pre-swizzled global source.
__global__ __launch_bounds__(256, 4) void k_attn(
    const unsigned short* __restrict__ Qb, const unsigned short* __restrict__ Kb,
    const unsigned short* __restrict__ Vt, unsigned short* __restrict__ O) {
  __shared__ unsigned short Ks[2][64 * 64];
  __shared__ unsigned short Vs[2][64 * 64];
  __shared__ unsigned short Ps[4][16 * 64];
  int tid = threadIdx.x;
  int w = tid >> 6, l = tid & 63;
  int lq = l & 15, lg = l >> 4;
  int bh = blockIdx.x;           // bh-major: head's blocks share an XCD
  int pi = blockIdx.y;           // 0..15
  int qtL = pi, qtH = 31 - pi;   // 64-row q-tile indices
  int nktL = qtL + 2;            // key-tiles needed: ceil((64*(qt+1)+Pn)/64)
  int nktH = qtH + 2;
  int qsA[2] = {qtL * 64, qtH * 64};

  // Q fragments: per stream, wave rows qs + w*16 + lq, cols ks*32 + lg*8
  bf16x8 qf[2][2];
#pragma unroll
  for (int qt = 0; qt < 2; ++qt) {
    const unsigned short* Qg = Qb + ((size_t)bh * Sq + qsA[qt] + w * 16) * DK;
#pragma unroll
    for (int ks = 0; ks < 2; ++ks)
      qf[qt][ks] = *reinterpret_cast<const bf16x8*>(
          Qg + (size_t)lq * DK + ks * 32 + lg * 8);
  }

  const unsigned short* Kg = Kb + (size_t)bh * SKPAD * DK;
  const unsigned short* Vg = Vt + (size_t)bh * DK * SKPAD;

  float m_run[2] = {-1e30f, -1e30f};
  float l_run[2] = {0.f, 0.f};
  f32x4 oacc[2][4];
#pragma unroll
  for (int qt = 0; qt < 2; ++qt)
#pragma unroll
    for (int n = 0; n < 4; ++n) oacc[qt][n] = (f32x4){0.f, 0.f, 0.f, 0.f};

  unsigned short* Pw = &Ps[w][0];

  auto STAGE = [&](int b, int t) {
    int kt = t * 64;
#pragma unroll
    for (int it = 0; it < 2; ++it) {
      int dst = (it * 256 + tid) * 16;
      int srcK = dst ^ (((dst >> 7) & 7) << 4);
      gload_lds16((const char*)(Kg + (size_t)kt * DK) + srcK,
                  (char*)Ks[b] + (size_t)(it * 256 + w * 64) * 16);
    }
#pragma unroll
    for (int it = 0; it < 2; ++it) {
      int dst = (it * 256 + tid) * 16;
      int row = dst >> 7;
      int colb = (dst & 127) ^ ((row & 7) << 4);
      gload_lds16((const char*)(Vg + (size_t)row * SKPAD + kt) + colb,
                  (char*)Vs[b] + (size_t)(it * 256 + w * 64) * 16);
    }
  };

  STAGE(0, 0);
  asm volatile("s_waitcnt vmcnt(0)" ::: "memory");
  __syncthreads();

  for (int t = 0; t < nktH; ++t) {
    int bsel = t & 1;
    if (t + 1 < nktH) STAGE(bsel ^ 1, t + 1);
    int kt = t * 64;

#pragma unroll
    for (int qt = 0; qt < 2; ++qt) {
      if (qt == 0 && t >= nktL) continue;          // light stream exhausted
      int qs = qsA[qt];
      if (kt > qs + w * 16 + 15 + Pn) continue;    // wave-uniform skip

      // S^T = K*Q : D[key][q], col q = lq, rows key = m*16 + lg*4 + r
      f32x4 st[4];
#pragma unroll
      for (int m = 0; m < 4; ++m) st[m] = (f32x4){0.f, 0.f, 0.f, 0.f};
      __builtin_amdgcn_s_setprio(1);
#pragma unroll
      for (int ks = 0; ks < 2; ++ks) {
#pragma unroll
        for (int m = 0; m < 4; ++m) {
          int krow = m * 16 + lq;
          int byt = (krow * 128 + ks * 64 + lg * 16) ^ ((krow & 7) << 4);
          bf16x8 kf = *reinterpret_cast<const bf16x8*>((const char*)Ks[bsel] + byt);
          st[m] = mfma16(kf, qf[qt][ks], st[m]);
        }
      }
      __builtin_amdgcn_s_setprio(0);

      // mask only near-diagonal fragments (wave-uniform branch)
      if (kt + 63 > qs + w * 16 + Pn) {
        int qrowP = qs + w * 16 + lq + Pn;
#pragma unroll
        for (int m = 0; m < 4; ++m)
#pragma unroll
          for (int r = 0; r < 4; ++r) {
            int key = kt + m * 16 + lg * 4 + r;
            st[m][r] = (key <= qrowP) ? st[m][r] : -1e30f;
          }
      }

      float mx = fmaxf(fmaxf(st[0][0], st[0][1]), fmaxf(st[0][2], st[0][3]));
#pragma unroll
      for (int m = 1; m < 4; ++m)
        mx = fmaxf(mx, fmaxf(fmaxf(st[m][0], st[m][1]), fmaxf(st[m][2], st[m][3])));
      mx = fmaxf(mx, __shfl_xor(mx, 16));
      mx = fmaxf(mx, __shfl_xor(mx, 32));
      if (__any(mx > m_run[qt] + 8.f)) {   // T13 defer-rescale
        float mnew = fmaxf(m_run[qt], mx);
        float alpha = exp2_fast(m_run[qt] - mnew);
        m_run[qt] = mnew;
        l_run[qt] *= alpha;
        float ar[4];
#pragma unroll
        for (int r = 0; r < 4; ++r) ar[r] = __shfl(alpha, lg * 4 + r);
#pragma unroll
        for (int n = 0; n < 4; ++n)
#pragma unroll
          for (int r = 0; r < 4; ++r) oacc[qt][n][r] *= ar[r];
      }
      float rs = 0.f;
#pragma unroll
      for (int m = 0; m < 4; ++m) {
        bf16x4 p4;
#pragma unroll
        for (int r = 0; r < 4; ++r) {
          float p = exp2_fast(st[m][r] - m_run[qt]);
          rs += p;
          p4[r] = (__bf16)p;               // native cast: compiler packs cvt
        }
        int byt = (lq * 128 + m * 32 + lg * 8) ^ ((lq & 7) << 4);
        *reinterpret_cast<bf16x4*>((char*)Pw + byt) = p4;
      }
      rs += __shfl_xor(rs, 16);
      rs += __shfl_xor(rs, 32);
      l_run[qt] += rs;

      // O[q][dv] += P[q][key] @ V[key][dv]
      __builtin_amdgcn_s_setprio(1);
#pragma unroll
      for (int ks = 0; ks < 2; ++ks) {
        int pbyt = (lq * 128 + ks * 64 + lg * 16) ^ ((lq & 7) << 4);
        bf16x8 pf = *reinterpret_cast<const bf16x8*>((const char*)Pw + pbyt);
#pragma unroll
        for (int n = 0; n < 4; ++n) {
          int dv = n * 16 + lq;
          int vbyt = (dv * 128 + ks * 64 + lg * 16) ^ ((dv & 7) << 4);
          bf16x8 vf = *reinterpret_cast<const bf16x8*>((const char*)Vs[bsel] + vbyt);
          oacc[qt][n] = mfma16(pf, vf, oacc[qt][n]);
        }
      }
      __builtin_amdgcn_s_setprio(0);
    }
    asm volatile("s_waitcnt vmcnt(0)" ::: "memory");
    __syncthreads();
  }

  int b = bh >> 4, h = bh & 15;
#pragma unroll
  for (int qt = 0; qt < 2; ++qt) {
    float lr[4];
#pragma unroll
    for (int r = 0; r < 4; ++r) lr[r] = 1.0f / __shfl(l_run[qt], lg * 4 + r);
#pragma unroll
    for (int n = 0; n < 4; ++n)
#pragma unroll
      for (int r = 0; r < 4; ++r) {
        int qrow2 = qsA[qt] + w * 16 + lg * 4 + r;
        size_t idx = ((size_t)b * Sq + qrow2) * Dd + h * DK + n * 16 + lq;
        O[idx] = f2bf(oacc[qt][n][r] * lr[r]);
      }
  }
}

extern "C" void kernel_launch(void* const* d_in, const int* in_sizes, int n_in,
                              void* d_out, int out_size, void* d_ws, size_t ws_size,
                              hipStream_t stream) {
  (void)in_sizes; (void)n_in; (void)out_size; (void)ws_size;
  const float* q  = (const float*)d_in[0];
  const float* k  = (const float*)d_in[1];
  const float* v  = (const float*)d_in[2];
  const float* Wq = (const float*)d_in[4];
  const float* bq = (const float*)d_in[5];
  const float* Wk = (const float*)d_in[6];
  const float* bk = (const float*)d_in[7];
  const float* Wv = (const float*)d_in[8];
  const float* bv = (const float*)d_in[9];
  const float* Wo = (const float*)d_in[10];
  const float* bo = (const float*)d_in[11];
  const float* pk = (const float*)d_in[12];
  const float* pv = (const float*)d_in[13];

  unsigned short* wsp = (unsigned short*)d_ws;
  size_t off = 0;
  auto take = [&](size_t elems) { unsigned short* p = wsp + off; off += elems; return p; };
  unsigned short* qc  = take(8388608);
  unsigned short* kc  = take(8388608);
  unsigned short* vc  = take(8388608);
  unsigned short* wqt = take(1048576);
  unsigned short* wkt = take(1048576);
  unsigned short* wvt = take(1048576);
  unsigned short* wot = take(1048576);
  unsigned short* Qbf = take(8388608);
  unsigned short* KbB = take((size_t)NBH * SKPAD * DK);
  unsigned short* VtB = take((size_t)NBH * DK * SKPAD);
  unsigned short* Ob  = qc;  // reuse: qc dead once attention runs
  float* outF = (float*)d_out;

  k_cvt3<<<dim3(1024, 3), 256, 0, stream>>>(q, k, v, qc, kc, vc, 8388608 / 4);
  k_wt<<<dim3(32, 32, 4), dim3(32, 8), 0, stream>>>(Wq, Wk, Wv, Wo, wqt, wkt, wvt, wot);
  k_fill<<<64, 256, 0, stream>>>(pk, pv, KbB, VtB);
  // Q scale folds 1/sqrt(dk) AND log2(e) for the exp2-domain softmax
  k_gemm<<<512, 256, 0, stream>>>(qc, wqt, bq, Qbf, nullptr, 0, 0.125f * LOG2E);
  k_gemm<<<512, 256, 0, stream>>>(kc, wkt, bk, KbB, nullptr, 1, 1.0f);
  k_gemm<<<512, 256, 0, stream>>>(vc, wvt, bv, VtB, nullptr, 2, 1.0f);
  k_attn<<<dim3(NBH, 16), 256, 0, stream>>>(Qbf, KbB, VtB, Ob);
  k_gemm<<<512, 256, 0, stream>>>(Ob, wot, bo, nullptr, outF, 3, 1.0f);
}

// Round 6
// 222.498 us; speedup vs baseline: 2.9122x; 1.1087x over previous
//
#include <hip/hip_runtime.h>

typedef __bf16 bf16x8 __attribute__((ext_vector_type(8)));
typedef __bf16 bf16x4 __attribute__((ext_vector_type(4)));
typedef float f32x4 __attribute__((ext_vector_type(4)));

constexpr int Sq = 2048, Dd = 1024, Hn = 16, Pn = 10, DK = 64;
constexpr int SKPAD = 2112;          // padded key axis (P + S = 2058 -> 2112)
constexpr int NBH = 64;              // B*H
constexpr float LOG2E = 1.44269504088896340736f;

__device__ __forceinline__ float exp2_fast(float x) {
  return __builtin_amdgcn_exp2f(x);  // v_exp_f32 computes 2^x natively
}

__device__ __forceinline__ unsigned short f2bf(float f) {
  unsigned int u = __float_as_uint(f);
  u += 0x7fffu + ((u >> 16) & 1u);   // RNE
  return (unsigned short)(u >> 16);
}

__device__ __forceinline__ void gload_lds16(const void* g, void* l) {
  __builtin_amdgcn_global_load_lds(
      (const __attribute__((address_space(1))) void*)g,
      (__attribute__((address_space(3))) void*)l, 16, 0, 0);
}

__device__ __forceinline__ f32x4 mfma16(bf16x8 a, bf16x8 b, f32x4 c) {
  return __builtin_amdgcn_mfma_f32_16x16x32_bf16(a, b, c, 0, 0, 0);
}

// ---------------- fp32 -> bf16 convert (3 tensors, one launch) ----------------
__global__ void k_cvt3(const float* __restrict__ i0, const float* __restrict__ i1,
                       const float* __restrict__ i2, unsigned short* __restrict__ o0,
                       unsigned short* __restrict__ o1, unsigned short* __restrict__ o2,
                       int n4) {
  const float* in; unsigned short* out;
  switch (blockIdx.y) {
    case 0: in = i0; out = o0; break;
    case 1: in = i1; out = o1; break;
    default: in = i2; out = o2; break;
  }
  int i = blockIdx.x * blockDim.x + threadIdx.x;
  int st = gridDim.x * blockDim.x;
  for (; i < n4; i += st) {
    float4 v = reinterpret_cast<const float4*>(in)[i];
    ushort4 r;
    r.x = f2bf(v.x); r.y = f2bf(v.y); r.z = f2bf(v.z); r.w = f2bf(v.w);
    reinterpret_cast<ushort4*>(out)[i] = r;
  }
}

// ---------------- W transpose + convert: Wt[n][k] = W[k][n] ----------------
__global__ void k_wt(const float* __restrict__ W0, const float* __restrict__ W1,
                     const float* __restrict__ W2, const float* __restrict__ W3,
                     unsigned short* __restrict__ T0, unsigned short* __restrict__ T1,
                     unsigned short* __restrict__ T2, unsigned short* __restrict__ T3) {
  __shared__ float tile[32][33];
  const float* W; unsigned short* T;
  switch (blockIdx.z) {
    case 0: W = W0; T = T0; break;
    case 1: W = W1; T = T1; break;
    case 2: W = W2; T = T2; break;
    default: W = W3; T = T3; break;
  }
  int n0 = blockIdx.x * 32, k0 = blockIdx.y * 32;
  int tx = threadIdx.x, ty = threadIdx.y;
  for (int r = ty; r < 32; r += 8)
    tile[r][tx] = W[(size_t)(k0 + r) * Dd + n0 + tx];
  __syncthreads();
  for (int r = ty; r < 32; r += 8)
    T[(size_t)(n0 + r) * Dd + k0 + tx] = f2bf(tile[tx][r]);
}

// ---------------- prefix K/V fill + zero padding ----------------
__global__ void k_fill(const float* __restrict__ pk, const float* __restrict__ pv,
                       unsigned short* __restrict__ Kb, unsigned short* __restrict__ Vt) {
  int bh = blockIdx.x;
  int h = bh & (Hn - 1);
  unsigned short* Kbh = Kb + (size_t)bh * SKPAD * DK;
  unsigned short* Vth = Vt + (size_t)bh * DK * SKPAD;
  for (int i = threadIdx.x; i < Pn * DK; i += blockDim.x) {
    int p = i >> 6, dk = i & 63;
    float kv = pk[((size_t)h * Pn + p) * DK + dk];
    float vv = pv[((size_t)h * Pn + p) * DK + dk];
    Kbh[p * DK + dk] = f2bf(kv);
    Vth[dk * SKPAD + p] = f2bf(vv);
  }
  constexpr int ZR = SKPAD - (Pn + Sq);  // 54 zero rows/cols
  for (int i = threadIdx.x; i < ZR * DK; i += blockDim.x) {
    int r = i >> 6, c = i & 63;
    Kbh[(Pn + Sq + r) * DK + c] = 0;
    Vth[c * SKPAD + (Pn + Sq + r)] = 0;
  }
}

// ---------------- GEMM body: C[M,1024] = A[M,1024] @ Bt^T + bias ----------------
// m97-exact single-buffer structure: STAGE -> vmcnt(0)+bar -> compute -> bar.
// 32 KB LDS -> 3-4 blocks/CU implicit TLP (the proven ~900 TF structure).
// mode 0: Q -> [B,H,S,DK] bf16 (scale folded)   mode 1: K -> [B,H,SKPAD,DK] at +P
// mode 2: V -> [B,H,DK,SKPAD] at +P (transposed) mode 3: fp32 row-major out
__device__ __forceinline__ void gemm_body(
    const unsigned short* __restrict__ A, const unsigned short* __restrict__ Bt,
    const float* __restrict__ bias, unsigned short* __restrict__ outB,
    float* __restrict__ outF, int mode, float scale,
    unsigned short* As, unsigned short* Bs) {
  int tid = threadIdx.x;
  int w = tid >> 6, l = tid & 63;
  int lq = l & 15, lg = l >> 4;
  int bx = blockIdx.x;
  int tm = bx >> 3, tn = bx & 7;
  int brow = tm * 128, bcol = tn * 128;
  int wm = w >> 1, wn = w & 1;

  f32x4 acc[4][4];
#pragma unroll
  for (int m = 0; m < 4; ++m)
#pragma unroll
    for (int n = 0; n < 4; ++n) acc[m][n] = (f32x4){0.f, 0.f, 0.f, 0.f};

  for (int kt = 0; kt < 1024; kt += 64) {
#pragma unroll
    for (int it = 0; it < 4; ++it) {
      int c = it * 256 + tid;
      int row = c >> 3, col = c & 7;
      gload_lds16(A + (size_t)(brow + row) * 1024 + kt + col * 8,
                  As + (size_t)(it * 256 + w * 64) * 8);
      gload_lds16(Bt + (size_t)(bcol + row) * 1024 + kt + col * 8,
                  Bs + (size_t)(it * 256 + w * 64) * 8);
    }
    asm volatile("s_waitcnt vmcnt(0)" ::: "memory");
    __syncthreads();
    const bf16x8* As8 = reinterpret_cast<const bf16x8*>(As);
    const bf16x8* Bs8 = reinterpret_cast<const bf16x8*>(Bs);
#pragma unroll
    for (int ks = 0; ks < 2; ++ks) {
      bf16x8 af[4], bfv[4];
#pragma unroll
      for (int m = 0; m < 4; ++m)
        af[m] = As8[(size_t)(wm * 64 + m * 16 + lq) * 8 + ks * 4 + lg];
#pragma unroll
      for (int n = 0; n < 4; ++n)
        bfv[n] = Bs8[(size_t)(wn * 64 + n * 16 + lq) * 8 + ks * 4 + lg];
#pragma unroll
      for (int m = 0; m < 4; ++m)
#pragma unroll
        for (int n = 0; n < 4; ++n)
          acc[m][n] = mfma16(af[m], bfv[n], acc[m][n]);
    }
    __syncthreads();
  }

#pragma unroll
  for (int n = 0; n < 4; ++n) {
    int N = bcol + wn * 64 + n * 16 + lq;
    float bv = bias[N];
#pragma unroll
    for (int m = 0; m < 4; ++m) {
      int M0 = brow + wm * 64 + m * 16 + lg * 4;
#pragma unroll
      for (int r = 0; r < 4; ++r) {
        float val = (acc[m][n][r] + bv) * scale;
        int Mr = M0 + r;
        if (mode == 3) {
          outF[(size_t)Mr * 1024 + N] = val;
        } else {
          int b = Mr >> 11, s = Mr & 2047;
          int h = N >> 6, dk = N & 63;
          size_t idx;
          if (mode == 0)      idx = (((size_t)(b * Hn + h)) * Sq + s) * DK + dk;
          else if (mode == 1) idx = (((size_t)(b * Hn + h)) * SKPAD + Pn + s) * DK + dk;
          else                idx = (((size_t)(b * Hn + h)) * DK + dk) * SKPAD + Pn + s;
          outB[idx] = f2bf(val);
        }
      }
    }
  }
}

// QKV projections fused into one launch: blockIdx.y picks the stream.
__global__ __launch_bounds__(256, 4) void k_gemm_qkv(
    const unsigned short* __restrict__ Aq, const unsigned short* __restrict__ Ak,
    const unsigned short* __restrict__ Av,
    const unsigned short* __restrict__ Wq, const unsigned short* __restrict__ Wk,
    const unsigned short* __restrict__ Wv,
    const float* __restrict__ bq, const float* __restrict__ bk,
    const float* __restrict__ bv,
    unsigned short* __restrict__ Qo, unsigned short* __restrict__ Ko,
    unsigned short* __restrict__ Vo, float qscale) {
  __shared__ unsigned short As[128 * 64];
  __shared__ unsigned short Bs[128 * 64];
  const unsigned short *A, *Bt; const float* bias; unsigned short* outB;
  int mode; float scale;
  switch (blockIdx.y) {
    case 0:  A = Aq; Bt = Wq; bias = bq; outB = Qo; mode = 0; scale = qscale; break;
    case 1:  A = Ak; Bt = Wk; bias = bk; outB = Ko; mode = 1; scale = 1.f; break;
    default: A = Av; Bt = Wv; bias = bv; outB = Vo; mode = 2; scale = 1.f; break;
  }
  gemm_body(A, Bt, bias, outB, nullptr, mode, scale, As, Bs);
}

// Output projection (fp32 out).
__global__ __launch_bounds__(256, 4) void k_gemm_o(
    const unsigned short* __restrict__ A, const unsigned short* __restrict__ Bt,
    const float* __restrict__ bias, float* __restrict__ outF) {
  __shared__ unsigned short As[128 * 64];
  __shared__ unsigned short Bs[128 * 64];
  gemm_body(A, Bt, bias, nullptr, outF, 3, 1.0f, As, Bs);
}

// ---------------- flash attention with prefix + causal mask ----------------
// Paired 64-row q-tiles {pi, 31-pi}: uniform 35 key-tiles/block; both streams
// share one K/V staging stream. bh-major grid for per-head L2 locality.
// 4 waves x 16 q-rows per stream, KVBLK=64 double-buffered 2-phase prefetch.
// Swapped QK^T (mfma(K,Q) -> S^T lane-local q), log2-domain online softmax.
// Softmax shfl diet: lane-local l partials (cross-lane sum deferred to
// epilogue); max shfls only inside the rare rescale branch (decision uses
// lane-local max; any offender triggers global-max rescale so P <= 2^8).
__global__ __launch_bounds__(256, 4) void k_attn(
    const unsigned short* __restrict__ Qb, const unsigned short* __restrict__ Kb,
    const unsigned short* __restrict__ Vt, unsigned short* __restrict__ O) {
  __shared__ unsigned short Ks[2][64 * 64];
  __shared__ unsigned short Vs[2][64 * 64];
  __shared__ unsigned short Ps[4][16 * 64];
  int tid = threadIdx.x;
  int w = tid >> 6, l = tid & 63;
  int lq = l & 15, lg = l >> 4;
  int bh = blockIdx.x;           // bh-major: head's blocks share an XCD
  int pi = blockIdx.y;           // 0..15
  int qtL = pi, qtH = 31 - pi;   // 64-row q-tile indices
  int nktL = qtL + 2;            // key-tiles needed: ceil((64*(qt+1)+Pn)/64)
  int nktH = qtH + 2;
  int qsA[2] = {qtL * 64, qtH * 64};

  // Q fragments: per stream, wave rows qs + w*16 + lq, cols ks*32 + lg*8
  bf16x8 qf[2][2];
#pragma unroll
  for (int qt = 0; qt < 2; ++qt) {
    const unsigned short* Qg = Qb + ((size_t)bh * Sq + qsA[qt] + w * 16) * DK;
#pragma unroll
    for (int ks = 0; ks < 2; ++ks)
      qf[qt][ks] = *reinterpret_cast<const bf16x8*>(
          Qg + (size_t)lq * DK + ks * 32 + lg * 8);
  }

  const unsigned short* Kg = Kb + (size_t)bh * SKPAD * DK;
  const unsigned short* Vg = Vt + (size_t)bh * DK * SKPAD;

  float m_run[2] = {-1e30f, -1e30f};
  float l_part[2] = {0.f, 0.f};      // lane-local partial denominators
  f32x4 oacc[2][4];
#pragma unroll
  for (int qt = 0; qt < 2; ++qt)
#pragma unroll
    for (int n = 0; n < 4; ++n) oacc[qt][n] = (f32x4){0.f, 0.f, 0.f, 0.f};

  unsigned short* Pw = &Ps[w][0];

  auto STAGE = [&](int b, int t) {
    int kt = t * 64;
#pragma unroll
    for (int it = 0; it < 2; ++it) {
      int dst = (it * 256 + tid) * 16;
      int srcK = dst ^ (((dst >> 7) & 7) << 4);
      gload_lds16((const char*)(Kg + (size_t)kt * DK) + srcK,
                  (char*)Ks[b] + (size_t)(it * 256 + w * 64) * 16);
    }
#pragma unroll
    for (int it = 0; it < 2; ++it) {
      int dst = (it * 256 + tid) * 16;
      int row = dst >> 7;
      int colb = (dst & 127) ^ ((row & 7) << 4);
      gload_lds16((const char*)(Vg + (size_t)row * SKPAD + kt) + colb,
                  (char*)Vs[b] + (size_t)(it * 256 + w * 64) * 16);
    }
  };

  STAGE(0, 0);
  asm volatile("s_waitcnt vmcnt(0)" ::: "memory");
  __syncthreads();

  for (int t = 0; t < nktH; ++t) {
    int bsel = t & 1;
    if (t + 1 < nktH) STAGE(bsel ^ 1, t + 1);
    int kt = t * 64;

#pragma unroll
    for (int qt = 0; qt < 2; ++qt) {
      if (qt == 0 && t >= nktL) continue;          // light stream exhausted
      int qs = qsA[qt];
      if (kt > qs + w * 16 + 15 + Pn) continue;    // wave-uniform skip

      // S^T = K*Q : D[key][q], col q = lq, rows key = m*16 + lg*4 + r
      f32x4 st[4];
#pragma unroll
      for (int m = 0; m < 4; ++m) st[m] = (f32x4){0.f, 0.f, 0.f, 0.f};
      __builtin_amdgcn_s_setprio(1);
#pragma unroll
      for (int ks = 0; ks < 2; ++ks) {
#pragma unroll
        for (int m = 0; m < 4; ++m) {
          int krow = m * 16 + lq;
          int byt = (krow * 128 + ks * 64 + lg * 16) ^ ((krow & 7) << 4);
          bf16x8 kf = *reinterpret_cast<const bf16x8*>((const char*)Ks[bsel] + byt);
          st[m] = mfma16(kf, qf[qt][ks], st[m]);
        }
      }
      __builtin_amdgcn_s_setprio(0);

      // mask only near-diagonal fragments (wave-uniform branch)
      if (kt + 63 > qs + w * 16 + Pn) {
        int qrowP = qs + w * 16 + lq + Pn;
#pragma unroll
        for (int m = 0; m < 4; ++m)
#pragma unroll
          for (int r = 0; r < 4; ++r) {
            int key = kt + m * 16 + lg * 4 + r;
            st[m][r] = (key <= qrowP) ? st[m][r] : -1e30f;
          }
      }

      // lane-local max over this lane's 16 scores
      float mx = fmaxf(fmaxf(st[0][0], st[0][1]), fmaxf(st[0][2], st[0][3]));
#pragma unroll
      for (int m = 1; m < 4; ++m)
        mx = fmaxf(mx, fmaxf(fmaxf(st[m][0], st[m][1]), fmaxf(st[m][2], st[m][3])));
      if (__any(mx > m_run[qt] + 8.f)) {   // T13 defer-rescale (rare path)
        float gmx = fmaxf(mx, __shfl_xor(mx, 16));
        gmx = fmaxf(gmx, __shfl_xor(gmx, 32));
        float mnew = fmaxf(m_run[qt], gmx);
        float alpha = exp2_fast(m_run[qt] - mnew);
        m_run[qt] = mnew;
        l_part[qt] *= alpha;
        float ar[4];
#pragma unroll
        for (int r = 0; r < 4; ++r) ar[r] = __shfl(alpha, lg * 4 + r);
#pragma unroll
        for (int n = 0; n < 4; ++n)
#pragma unroll
          for (int r = 0; r < 4; ++r) oacc[qt][n][r] *= ar[r];
      }
      float rs = 0.f;
#pragma unroll
      for (int m = 0; m < 4; ++m) {
        bf16x4 p4;
#pragma unroll
        for (int r = 0; r < 4; ++r) {
          float p = exp2_fast(st[m][r] - m_run[qt]);
          rs += p;
          p4[r] = (__bf16)p;               // native cast: compiler packs cvt
        }
        int byt = (lq * 128 + m * 32 + lg * 8) ^ ((lq & 7) << 4);
        *reinterpret_cast<bf16x4*>((char*)Pw + byt) = p4;
      }
      l_part[qt] += rs;                    // no cross-lane sum here

      // O[q][dv] += P[q][key] @ V[key][dv]
      __builtin_amdgcn_s_setprio(1);
#pragma unroll
      for (int ks = 0; ks < 2; ++ks) {
        int pbyt = (lq * 128 + ks * 64 + lg * 16) ^ ((lq & 7) << 4);
        bf16x8 pf = *reinterpret_cast<const bf16x8*>((const char*)Pw + pbyt);
#pragma unroll
        for (int n = 0; n < 4; ++n) {
          int dv = n * 16 + lq;
          int vbyt = (dv * 128 + ks * 64 + lg * 16) ^ ((dv & 7) << 4);
          bf16x8 vf = *reinterpret_cast<const bf16x8*>((const char*)Vs[bsel] + vbyt);
          oacc[qt][n] = mfma16(pf, vf, oacc[qt][n]);
        }
      }
      __builtin_amdgcn_s_setprio(0);
    }
    asm volatile("s_waitcnt vmcnt(0)" ::: "memory");
    __syncthreads();
  }

  int b = bh >> 4, h = bh & 15;
#pragma unroll
  for (int qt = 0; qt < 2; ++qt) {
    float ls = l_part[qt];                 // cross-lane denominator sum (once)
    ls += __shfl_xor(ls, 16);
    ls += __shfl_xor(ls, 32);
    float lr[4];
#pragma unroll
    for (int r = 0; r < 4; ++r) lr[r] = 1.0f / __shfl(ls, lg * 4 + r);
#pragma unroll
    for (int n = 0; n < 4; ++n)
#pragma unroll
      for (int r = 0; r < 4; ++r) {
        int qrow2 = qsA[qt] + w * 16 + lg * 4 + r;
        size_t idx = ((size_t)b * Sq + qrow2) * Dd + h * DK + n * 16 + lq;
        O[idx] = f2bf(oacc[qt][n][r] * lr[r]);
      }
  }
}

extern "C" void kernel_launch(void* const* d_in, const int* in_sizes, int n_in,
                              void* d_out, int out_size, void* d_ws, size_t ws_size,
                              hipStream_t stream) {
  (void)in_sizes; (void)n_in; (void)out_size; (void)ws_size;
  const float* q  = (const float*)d_in[0];
  const float* k  = (const float*)d_in[1];
  const float* v  = (const float*)d_in[2];
  const float* Wq = (const float*)d_in[4];
  const float* bq = (const float*)d_in[5];
  const float* Wk = (const float*)d_in[6];
  const float* bk = (const float*)d_in[7];
  const float* Wv = (const float*)d_in[8];
  const float* bv = (const float*)d_in[9];
  const float* Wo = (const float*)d_in[10];
  const float* bo = (const float*)d_in[11];
  const float* pk = (const float*)d_in[12];
  const float* pv = (const float*)d_in[13];

  unsigned short* wsp = (unsigned short*)d_ws;
  size_t off = 0;
  auto take = [&](size_t elems) { unsigned short* p = wsp + off; off += elems; return p; };
  unsigned short* qc  = take(8388608);
  unsigned short* kc  = take(8388608);
  unsigned short* vc  = take(8388608);
  unsigned short* wqt = take(1048576);
  unsigned short* wkt = take(1048576);
  unsigned short* wvt = take(1048576);
  unsigned short* wot = take(1048576);
  unsigned short* Qbf = take(8388608);
  unsigned short* KbB = take((size_t)NBH * SKPAD * DK);
  unsigned short* VtB = take((size_t)NBH * DK * SKPAD);
  unsigned short* Ob  = qc;  // reuse: qc dead once attention runs
  float* outF = (float*)d_out;

  k_cvt3<<<dim3(1024, 3), 256, 0, stream>>>(q, k, v, qc, kc, vc, 8388608 / 4);
  k_wt<<<dim3(32, 32, 4), dim3(32, 8), 0, stream>>>(Wq, Wk, Wv, Wo, wqt, wkt, wvt, wot);
  k_fill<<<64, 256, 0, stream>>>(pk, pv, KbB, VtB);
  // Q scale folds 1/sqrt(dk) AND log2(e) for the exp2-domain softmax
  k_gemm_qkv<<<dim3(512, 3), 256, 0, stream>>>(qc, kc, vc, wqt, wkt, wvt,
                                               bq, bk, bv, Qbf, KbB, VtB,
                                               0.125f * LOG2E);
  k_attn<<<dim3(NBH, 16), 256, 0, stream>>>(Qbf, KbB, VtB, Ob);
  k_gemm_o<<<512, 256, 0, stream>>>(Ob, wot, bo, outF);
}